// Round 2
// baseline (1367.591 us; speedup 1.0000x reference)
//
#include <hip/hip_runtime.h>

#define B_ 8
#define C_ 256
#define H_ 128
#define W_ 128
#define NH_ 8
#define WS_ 8
#define HD_ 32
#define WN_ 16
#define NWIN_ 256
#define HW_ 16384

// ---------- kernel 1: 8x8 window mean-pool + leaky relu ----------
__global__ __launch_bounds__(256) void pool_kernel(const float* __restrict__ x, float* __restrict__ xp) {
    int bc = blockIdx.x;           // b*C + c
    int t = threadIdx.x;           // 0..255 ; t = wy*16+wx
    int wx = t & 15, wy = t >> 4;
    const float* src = x + (size_t)bc * HW_ + (size_t)(wy*8)*W_ + wx*8;
    float s = 0.f;
    #pragma unroll
    for (int ii = 0; ii < 8; ++ii) {
        const float4* r = (const float4*)(src + (size_t)ii*W_);
        float4 a = r[0], b = r[1];
        s += a.x+a.y+a.z+a.w + b.x+b.y+b.z+b.w;
    }
    s *= (1.f/64.f);
    xp[(size_t)bc*256 + t] = s > 0.f ? s : 0.01f*s;
}

// ---------- kernel 2: per-window sampling params {ox, oy, sx, sy} ----------
__global__ __launch_bounds__(256) void params_kernel(const float* __restrict__ xp,
                              const float* __restrict__ bias_w, const float* __restrict__ bias_b,
                              const float* __restrict__ scale_w, const float* __restrict__ scale_b,
                              float* __restrict__ params) {
    __shared__ float xs[256];
    int blk = blockIdx.x;          // b*256 + win
    int b = blk >> 8, win = blk & 255;
    int t = threadIdx.x;
    xs[t] = xp[((size_t)(b*256 + t))*256 + win];
    __syncthreads();
    if (t < 32) {
        int which = t >> 4;        // 0: bias, 1: scale
        int o = t & 15;
        const float* Wm = which ? scale_w : bias_w;
        float acc = which ? scale_b[o] : bias_b[o];
        for (int c = 0; c < 256; ++c) acc += Wm[o*256 + c] * xs[c];
        int nh = o >> 1, comp = o & 1;
        int n = b*8 + nh;
        // bias: ox = 63.5 * (bias/16) = 3.96875*bias ; scale stored raw
        float v = which ? acc : 3.96875f * acc;
        params[((size_t)(n*256 + win))*4 + which*2 + comp] = v;
    }
}

// ---------- kernel 3/5: GEMM out[o][p] = W[o,:].X[:,p] + bias[o]  (one batch image) ----------
// W: (Ot, 256) row-major ; X: (256, 16384) ; out: (Ot, 16384)
__global__ __launch_bounds__(256) void gemm_kernel(const float* __restrict__ Wm, const float* __restrict__ X,
                            const float* __restrict__ bias, float* __restrict__ out,
                            int Ot) {
    __shared__ __align__(16) float As[16][128];  // [k][o]
    __shared__ __align__(16) float Bs[16][64];   // [k][p]
    int p0 = blockIdx.x * 64;
    int o0 = blockIdx.y * 128;
    int t = threadIdx.x;
    float acc[8][4];
    #pragma unroll
    for (int i=0;i<8;++i)
        #pragma unroll
        for(int j=0;j<4;++j) acc[i][j]=0.f;
    int oL = (t >> 4) * 8;
    int pL = (t & 15) * 4;
    for (int k0 = 0; k0 < 256; k0 += 16) {
        {   // A chunk: 128 o x 16 k, transposed into LDS
            int o = t >> 1, kk = (t & 1) * 8;
            const float4* src = (const float4*)(Wm + (size_t)(o0+o)*256 + k0 + kk);
            float4 a = src[0], c = src[1];
            As[kk+0][o]=a.x; As[kk+1][o]=a.y; As[kk+2][o]=a.z; As[kk+3][o]=a.w;
            As[kk+4][o]=c.x; As[kk+5][o]=c.y; As[kk+6][o]=c.z; As[kk+7][o]=c.w;
        }
        {   // B chunk: 16 k x 64 p
            int kk = t >> 4, pp2 = (t & 15) * 4;
            *(float4*)&Bs[kk][pp2] = *(const float4*)(X + (size_t)(k0+kk)*HW_ + p0 + pp2);
        }
        __syncthreads();
        #pragma unroll
        for (int k = 0; k < 16; ++k) {
            float4 b4 = *(const float4*)&Bs[k][pL];
            float4 a0 = *(const float4*)&As[k][oL];
            float4 a1 = *(const float4*)&As[k][oL+4];
            float av[8] = {a0.x,a0.y,a0.z,a0.w,a1.x,a1.y,a1.z,a1.w};
            float bv[4] = {b4.x,b4.y,b4.z,b4.w};
            #pragma unroll
            for (int i=0;i<8;++i)
                #pragma unroll
                for (int j=0;j<4;++j)
                    acc[i][j] += av[i]*bv[j];
        }
        __syncthreads();
    }
    #pragma unroll
    for (int i=0;i<8;++i) {
        float bb = bias[o0+oL+i];
        float4 v = {acc[i][0]+bb, acc[i][1]+bb, acc[i][2]+bb, acc[i][3]+bb};
        *(float4*)(out + (size_t)(o0+oL+i)*HW_ + p0 + pL) = v;
    }
}

// ---------- kernel 4: fused bilinear sampling + windowed attention (one batch image) ----------
__global__ __launch_bounds__(256) void attn_kernel(const float* __restrict__ qkvb,
                            const float* __restrict__ params_,
                            const float* __restrict__ rpb_table,
                            float* __restrict__ attnout, int b) {
    __shared__ __align__(16) float q_s[32][68];  // [d][tok]
    __shared__ __align__(16) float k_s[32][68];
    __shared__ __align__(16) float v_s[32][68];
    __shared__ __align__(16) float S[64][65];    // [q][k]
    __shared__ float red[4][64];
    __shared__ float rowm[64], rowinv[64];

    int blk = blockIdx.x;            // nh*256 + win
    int nh = blk >> 8, win = blk & 255;
    int wy = win >> 4, wx = win & 15;
    int t = threadIdx.x;

    const float* pp = params_ + ((size_t)((b*8 + nh)*256 + win))*4;
    float ox = pp[0], oy = pp[1], sx = pp[2], sy = pp[3];

    const float* qbase = qkvb + (size_t)(nh*32) * HW_;
    const float* kbase = qbase + (size_t)256*HW_;
    const float* vbase = qbase + (size_t)512*HW_;

    {   // load q into LDS [d][tok]
        int tok = t >> 2, dg = (t & 3)*8;
        int i = tok >> 3, j = tok & 7;
        size_t sp = (size_t)(wy*8 + i)*W_ + wx*8 + j;
        #pragma unroll
        for (int e = 0; e < 8; ++e) {
            int d = dg + e;
            q_s[d][tok] = qbase[(size_t)d*HW_ + sp];
        }
    }
    {   // bilinear-sample k,v into LDS [d][tok]
        int tok = t >> 2, dg = (t & 3)*8;
        int i = tok >> 3, j = tok & 7;
        int h = wy*8 + i, w = wx*8 + j;
        float gx = (float)w + ((float)j - 3.5f)*sx + ox;
        float gy = (float)h + ((float)i - 3.5f)*sy + oy;
        float x0f = floorf(gx), y0f = floorf(gy);
        int x0 = (int)x0f, y0 = (int)y0f;
        float wx1 = gx - x0f, wy1 = gy - y0f;
        float wxz = 1.f - wx1, wyz = 1.f - wy1;
        int x1 = x0 + 1, y1 = y0 + 1;
        float m00 = wyz*wxz * ((y0>=0 && y0<H_ && x0>=0 && x0<W_) ? 1.f : 0.f);
        float m01 = wyz*wx1 * ((y0>=0 && y0<H_ && x1>=0 && x1<W_) ? 1.f : 0.f);
        float m10 = wy1*wxz * ((y1>=0 && y1<H_ && x0>=0 && x0<W_) ? 1.f : 0.f);
        float m11 = wy1*wx1 * ((y1>=0 && y1<H_ && x1>=0 && x1<W_) ? 1.f : 0.f);
        int x0c = min(max(x0,0),W_-1), x1c = min(max(x1,0),W_-1);
        int y0c = min(max(y0,0),H_-1), y1c = min(max(y1,0),H_-1);
        size_t p00 = (size_t)y0c*W_ + x0c, p01 = (size_t)y0c*W_ + x1c;
        size_t p10 = (size_t)y1c*W_ + x0c, p11 = (size_t)y1c*W_ + x1c;
        #pragma unroll
        for (int e = 0; e < 8; ++e) {
            int d = dg + e;
            const float* kp = kbase + (size_t)d*HW_;
            const float* vp = vbase + (size_t)d*HW_;
            k_s[d][tok] = m00*kp[p00] + m01*kp[p01] + m10*kp[p10] + m11*kp[p11];
            v_s[d][tok] = m00*vp[p00] + m01*vp[p01] + m10*vp[p10] + m11*vp[p11];
        }
    }
    __syncthreads();

    const float scale = 0.17677669529663687f;  // 32^-0.5
    {   // S = q.kT * scale + rpb  (outer product over d)
        int qi0 = (t & 15)*4, ki0 = (t >> 4)*4;
        float acc[4][4];
        #pragma unroll
        for (int a=0;a<4;++a)
            #pragma unroll
            for (int c=0;c<4;++c) acc[a][c]=0.f;
        #pragma unroll
        for (int d = 0; d < 32; ++d) {
            float4 qv = *(const float4*)&q_s[d][qi0];
            float4 kv = *(const float4*)&k_s[d][ki0];
            float qa[4]={qv.x,qv.y,qv.z,qv.w}, ka[4]={kv.x,kv.y,kv.z,kv.w};
            #pragma unroll
            for (int a=0;a<4;++a)
                #pragma unroll
                for (int c=0;c<4;++c) acc[a][c] += qa[a]*ka[c];
        }
        #pragma unroll
        for (int a=0;a<4;++a) {
            int qi = qi0+a; int yq = qi>>3, xq = qi&7;
            #pragma unroll
            for (int c=0;c<4;++c) {
                int ki = ki0+c; int yk = ki>>3, xk = ki&7;
                int idx = (yq-yk+7)*15 + (xq-xk+7);
                S[qi][ki] = acc[a][c]*scale + rpb_table[idx*8 + nh];
            }
        }
    }
    __syncthreads();
    {   // row max (partial)
        int r = t & 63, part = t >> 6;
        float m = -1e30f;
        #pragma unroll
        for (int c = 0; c < 16; ++c) m = fmaxf(m, S[r][part*16+c]);
        red[part][r] = m;
    }
    __syncthreads();
    if (t < 64) rowm[t] = fmaxf(fmaxf(red[0][t],red[1][t]),fmaxf(red[2][t],red[3][t]));
    __syncthreads();
    {   // exp + partial sum
        int r = t & 63, part = t >> 6;
        float m = rowm[r], s = 0.f;
        #pragma unroll
        for (int c = 0; c < 16; ++c) {
            float e = __expf(S[r][part*16+c] - m);
            S[r][part*16+c] = e;
            s += e;
        }
        red[part][r] = s;
    }
    __syncthreads();
    if (t < 64) rowinv[t] = 1.f / (red[0][t]+red[1][t]+red[2][t]+red[3][t]);
    __syncthreads();
    {   // out[q][d] = sum_k P[q][k] v[k][d] ; write un-windowed (nh*32+d, h, w)
        int qi0 = (t & 15)*4, d0 = (t >> 4)*2;
        float acc[4][2];
        #pragma unroll
        for (int a=0;a<4;++a) { acc[a][0]=0.f; acc[a][1]=0.f; }
        for (int k = 0; k < 64; ++k) {
            float v0 = v_s[d0][k], v1 = v_s[d0+1][k];
            #pragma unroll
            for (int a=0;a<4;++a) {
                float pv = S[qi0+a][k];
                acc[a][0] += pv*v0; acc[a][1] += pv*v1;
            }
        }
        #pragma unroll
        for (int a=0;a<4;++a) {
            int qi = qi0+a;
            float inv = rowinv[qi];
            int i = qi>>3, j = qi&7;
            size_t sp = (size_t)(wy*8+i)*W_ + wx*8 + j;
            attnout[((size_t)(nh*32 + d0  ))*HW_ + sp] = acc[a][0]*inv;
            attnout[((size_t)(nh*32 + d0+1))*HW_ + sp] = acc[a][1]*inv;
        }
    }
}

extern "C" void kernel_launch(void* const* d_in, const int* in_sizes, int n_in,
                              void* d_out, int out_size, void* d_ws, size_t ws_size,
                              hipStream_t stream) {
    const float* x       = (const float*)d_in[0];
    const float* qkv_w   = (const float*)d_in[1];
    const float* qkv_b   = (const float*)d_in[2];
    const float* bias_w  = (const float*)d_in[3];
    const float* bias_b  = (const float*)d_in[4];
    const float* scale_w = (const float*)d_in[5];
    const float* scale_b = (const float*)d_in[6];
    const float* proj_w  = (const float*)d_in[7];
    const float* proj_b  = (const float*)d_in[8];
    const float* rpb     = (const float*)d_in[9];
    float* out = (float*)d_out;

    // per-b workspace layout (fits in ~70 MB):
    float* ws = (float*)d_ws;
    float* xp      = ws;                      // 524288 floats
    float* params  = xp + 524288;             // 65536 floats
    float* qkvbuf  = params + 65536;          // 12582912 floats (768, HW) one image
    float* attnout = qkvbuf + 12582912;       // 4194304 floats (256, HW) one image

    pool_kernel  <<<dim3(B_*C_),    256, 0, stream>>>(x, xp);
    params_kernel<<<dim3(B_*NWIN_), 256, 0, stream>>>(xp, bias_w, bias_b, scale_w, scale_b, params);
    for (int b = 0; b < B_; ++b) {
        const float* xb = x + (size_t)b*C_*HW_;
        gemm_kernel<<<dim3(256, 6, 1), 256, 0, stream>>>(qkv_w, xb, qkv_b, qkvbuf, 768);
        attn_kernel<<<dim3(NH_*NWIN_), 256, 0, stream>>>(qkvbuf, params, rpb, attnout, b);
        gemm_kernel<<<dim3(256, 2, 1), 256, 0, stream>>>(proj_w, attnout, proj_b, out + (size_t)b*C_*HW_, 256);
    }
}

// Round 3
// 886.718 us; speedup vs baseline: 1.5423x; 1.5423x over previous
//
#include <hip/hip_runtime.h>

#define B_ 8
#define C_ 256
#define H_ 128
#define W_ 128
#define NH_ 8
#define WS_ 8
#define HD_ 32
#define WN_ 16
#define NWIN_ 256
#define HW_ 16384

typedef unsigned short ushort_t;
typedef unsigned int uint_t;
typedef __attribute__((ext_vector_type(8))) short short8;
typedef __attribute__((ext_vector_type(4))) float f32x4;

__device__ __forceinline__ ushort_t bf16_rtn(float x) {
    uint_t u = __float_as_uint(x);
    return (ushort_t)((u + 0x7FFFu + ((u >> 16) & 1u)) >> 16);
}
__device__ __forceinline__ float bf16_tof(ushort_t h) {
    return __uint_as_float(((uint_t)h) << 16);
}

// ---------- kernel 1: 8x8 window mean-pool + leaky relu ----------
__global__ __launch_bounds__(256) void pool_kernel(const float* __restrict__ x, float* __restrict__ xp) {
    int bc = blockIdx.x;
    int t = threadIdx.x;
    int wx = t & 15, wy = t >> 4;
    const float* src = x + (size_t)bc * HW_ + (size_t)(wy*8)*W_ + wx*8;
    float s = 0.f;
    #pragma unroll
    for (int ii = 0; ii < 8; ++ii) {
        const float4* r = (const float4*)(src + (size_t)ii*W_);
        float4 a = r[0], b = r[1];
        s += a.x+a.y+a.z+a.w + b.x+b.y+b.z+b.w;
    }
    s *= (1.f/64.f);
    xp[(size_t)bc*256 + t] = s > 0.f ? s : 0.01f*s;
}

// ---------- kernel 2: per-window sampling params {ox, oy, sx, sy} ----------
__global__ __launch_bounds__(256) void params_kernel(const float* __restrict__ xp,
                              const float* __restrict__ bias_w, const float* __restrict__ bias_b,
                              const float* __restrict__ scale_w, const float* __restrict__ scale_b,
                              float* __restrict__ params) {
    __shared__ float xs[256];
    int blk = blockIdx.x;
    int b = blk >> 8, win = blk & 255;
    int t = threadIdx.x;
    xs[t] = xp[((size_t)(b*256 + t))*256 + win];
    __syncthreads();
    if (t < 32) {
        int which = t >> 4;
        int o = t & 15;
        const float* Wm = which ? scale_w : bias_w;
        float acc = which ? scale_b[o] : bias_b[o];
        for (int c = 0; c < 256; ++c) acc += Wm[o*256 + c] * xs[c];
        int nh = o >> 1, comp = o & 1;
        int n = b*8 + nh;
        float v = which ? acc : 3.96875f * acc;
        params[((size_t)(n*256 + win))*4 + which*2 + comp] = v;
    }
}

// ---------- weight f32 -> bf16 hi/lo split (same [o][c] layout) ----------
__global__ __launch_bounds__(256) void wconv_kernel(const float* __restrict__ w,
                            ushort_t* __restrict__ wh, ushort_t* __restrict__ wl, int n4) {
    int i = blockIdx.x*256 + threadIdx.x;
    if (i >= n4) return;
    float4 v = ((const float4*)w)[i];
    float vv[4] = {v.x, v.y, v.z, v.w};
    uint_t hp[2], lp[2];
    ushort_t h[4], l[4];
    #pragma unroll
    for (int e = 0; e < 4; ++e) {
        h[e] = bf16_rtn(vv[e]);
        l[e] = bf16_rtn(vv[e] - bf16_tof(h[e]));
    }
    hp[0] = (uint_t)h[0] | ((uint_t)h[1] << 16); hp[1] = (uint_t)h[2] | ((uint_t)h[3] << 16);
    lp[0] = (uint_t)l[0] | ((uint_t)l[1] << 16); lp[1] = (uint_t)l[2] | ((uint_t)l[3] << 16);
    ((uint2*)wh)[i] = make_uint2(hp[0], hp[1]);
    ((uint2*)wl)[i] = make_uint2(lp[0], lp[1]);
}

// ---------- transpose + split: x[c][p] f32 -> xt_hi/xt_lo [p][c] bf16 (one image) ----------
__global__ __launch_bounds__(256) void transpose_split_kernel(const float* __restrict__ xsrc,
                            ushort_t* __restrict__ th, ushort_t* __restrict__ tl) {
    __shared__ float tile[64][65];
    int p0 = blockIdx.x * 64, c0 = blockIdx.y * 64;
    int t = threadIdx.x;
    #pragma unroll
    for (int r = 0; r < 4; ++r) {
        int task = t + r*256;
        int cl = task >> 4, p4 = (task & 15) * 4;
        float4 v = *(const float4*)(xsrc + (size_t)(c0+cl)*HW_ + p0 + p4);
        tile[cl][p4+0] = v.x; tile[cl][p4+1] = v.y; tile[cl][p4+2] = v.z; tile[cl][p4+3] = v.w;
    }
    __syncthreads();
    #pragma unroll
    for (int r = 0; r < 2; ++r) {
        int task = t + r*256;
        int pl = task >> 3, cb = (task & 7) * 8;
        ushort_t h[8], l[8];
        #pragma unroll
        for (int e = 0; e < 8; ++e) {
            float v = tile[cb+e][pl];
            h[e] = bf16_rtn(v);
            l[e] = bf16_rtn(v - bf16_tof(h[e]));
        }
        uint4 H, L;
        H.x = (uint_t)h[0]|((uint_t)h[1]<<16); H.y = (uint_t)h[2]|((uint_t)h[3]<<16);
        H.z = (uint_t)h[4]|((uint_t)h[5]<<16); H.w = (uint_t)h[6]|((uint_t)h[7]<<16);
        L.x = (uint_t)l[0]|((uint_t)l[1]<<16); L.y = (uint_t)l[2]|((uint_t)l[3]<<16);
        L.z = (uint_t)l[4]|((uint_t)l[5]<<16); L.w = (uint_t)l[6]|((uint_t)l[7]<<16);
        *(uint4*)(th + (size_t)(p0+pl)*256 + c0 + cb) = H;
        *(uint4*)(tl + (size_t)(p0+pl)*256 + c0 + cb) = L;
    }
}

// ---------- MFMA split-bf16 GEMM: out[o][p] = sum_c W[o][c] X[c][p] + bias[o] ----------
// wh/wl: [M][256] bf16 ; xh/xl: [16384][256] bf16 (i.e. X^T) ; out: [M][16384] f32
__global__ __launch_bounds__(256) void mgemm_kernel(const ushort_t* __restrict__ wh, const ushort_t* __restrict__ wl,
                            const ushort_t* __restrict__ xh, const ushort_t* __restrict__ xl,
                            const float* __restrict__ bias, float* __restrict__ out) {
    __shared__ uint4 Ah[1024], Al[1024], Bh[1024], Bl[1024];  // 64 KB total
    int p0 = blockIdx.x * 128, o0 = blockIdx.y * 128;
    int t = threadIdx.x;
    int lane = t & 63, wid = t >> 6;
    int wm = wid >> 1, wn = wid & 1;
    int q = lane >> 4, rl = lane & 15;

    f32x4 acc[4][4];
    #pragma unroll
    for (int f = 0; f < 4; ++f)
        #pragma unroll
        for (int g = 0; g < 4; ++g)
            acc[f][g] = (f32x4){0.f, 0.f, 0.f, 0.f};

    int srow = t >> 1, shalf = t & 1;
    int sw = srow & 7;

    for (int ks = 0; ks < 4; ++ks) {
        int c0 = ks * 64;
        __syncthreads();
        {   // stage tiles (reg -> swizzled LDS); 16B units, unit' = unit ^ (row&7)
            const uint4* a_h = (const uint4*)(wh + (size_t)(o0+srow)*256 + c0);
            const uint4* a_l = (const uint4*)(wl + (size_t)(o0+srow)*256 + c0);
            const uint4* b_h = (const uint4*)(xh + (size_t)(p0+srow)*256 + c0);
            const uint4* b_l = (const uint4*)(xl + (size_t)(p0+srow)*256 + c0);
            #pragma unroll
            for (int jj = 0; jj < 4; ++jj) {
                int u = shalf*4 + jj;
                int d = srow*8 + (u ^ sw);
                Ah[d] = a_h[u]; Al[d] = a_l[u];
                Bh[d] = b_h[u]; Bl[d] = b_l[u];
            }
        }
        __syncthreads();
        #pragma unroll
        for (int kk = 0; kk < 2; ++kk) {
            short8 afh[4], afl[4], bfh[4], bfl[4];
            #pragma unroll
            for (int f = 0; f < 4; ++f) {
                int row = wm*64 + f*16 + rl;
                int u = (kk*4 + q) ^ (row & 7);
                afh[f] = __builtin_bit_cast(short8, Ah[row*8 + u]);
                afl[f] = __builtin_bit_cast(short8, Al[row*8 + u]);
            }
            #pragma unroll
            for (int g = 0; g < 4; ++g) {
                int row = wn*64 + g*16 + rl;
                int u = (kk*4 + q) ^ (row & 7);
                bfh[g] = __builtin_bit_cast(short8, Bh[row*8 + u]);
                bfl[g] = __builtin_bit_cast(short8, Bl[row*8 + u]);
            }
            #pragma unroll
            for (int f = 0; f < 4; ++f)
                #pragma unroll
                for (int g = 0; g < 4; ++g) {
                    acc[f][g] = __builtin_amdgcn_mfma_f32_16x16x32_bf16(afh[f], bfh[g], acc[f][g], 0, 0, 0);
                    acc[f][g] = __builtin_amdgcn_mfma_f32_16x16x32_bf16(afh[f], bfl[g], acc[f][g], 0, 0, 0);
                    acc[f][g] = __builtin_amdgcn_mfma_f32_16x16x32_bf16(afl[f], bfh[g], acc[f][g], 0, 0, 0);
                }
        }
    }
    // epilogue: D row = o (arg0 side), col = p (arg1 side); row=(lane>>4)*4+r, col=lane&15
    #pragma unroll
    for (int f = 0; f < 4; ++f) {
        float4 bb = *(const float4*)&bias[o0 + wm*64 + f*16 + q*4];
        float bbv[4] = {bb.x, bb.y, bb.z, bb.w};
        #pragma unroll
        for (int g = 0; g < 4; ++g) {
            int p = p0 + wn*64 + g*16 + rl;
            #pragma unroll
            for (int r = 0; r < 4; ++r) {
                int o = o0 + wm*64 + f*16 + q*4 + r;
                out[(size_t)o*HW_ + p] = acc[f][g][r] + bbv[r];
            }
        }
    }
}

// ---------- kernel 4: fused bilinear sampling + windowed attention (one image) ----------
// outputs attn result as bf16 hi/lo in [p][c] layout (ready for proj mgemm)
__global__ __launch_bounds__(256) void attn_kernel(const float* __restrict__ qkvb,
                            const float* __restrict__ params_,
                            const float* __restrict__ rpb_table,
                            ushort_t* __restrict__ ath, ushort_t* __restrict__ atl, int b) {
    __shared__ __align__(16) float q_s[32][68];
    __shared__ __align__(16) float k_s[32][68];
    __shared__ __align__(16) float v_s[32][68];
    __shared__ __align__(16) float S[64][65];
    __shared__ float red[4][64];
    __shared__ float rowm[64], rowinv[64];

    int blk = blockIdx.x;
    int nh = blk >> 8, win = blk & 255;
    int wy = win >> 4, wx = win & 15;
    int t = threadIdx.x;

    const float* pp = params_ + ((size_t)((b*8 + nh)*256 + win))*4;
    float ox = pp[0], oy = pp[1], sx = pp[2], sy = pp[3];

    const float* qbase = qkvb + (size_t)(nh*32) * HW_;
    const float* kbase = qbase + (size_t)256*HW_;
    const float* vbase = qbase + (size_t)512*HW_;

    {   // load q into LDS [d][tok]
        int tok = t >> 2, dg = (t & 3)*8;
        int i = tok >> 3, j = tok & 7;
        size_t sp = (size_t)(wy*8 + i)*W_ + wx*8 + j;
        #pragma unroll
        for (int e = 0; e < 8; ++e) {
            int d = dg + e;
            q_s[d][tok] = qbase[(size_t)d*HW_ + sp];
        }
    }
    {   // bilinear-sample k,v into LDS [d][tok]
        int tok = t >> 2, dg = (t & 3)*8;
        int i = tok >> 3, j = tok & 7;
        int h = wy*8 + i, w = wx*8 + j;
        float gx = (float)w + ((float)j - 3.5f)*sx + ox;
        float gy = (float)h + ((float)i - 3.5f)*sy + oy;
        float x0f = floorf(gx), y0f = floorf(gy);
        int x0 = (int)x0f, y0 = (int)y0f;
        float wx1 = gx - x0f, wy1 = gy - y0f;
        float wxz = 1.f - wx1, wyz = 1.f - wy1;
        int x1 = x0 + 1, y1 = y0 + 1;
        float m00 = wyz*wxz * ((y0>=0 && y0<H_ && x0>=0 && x0<W_) ? 1.f : 0.f);
        float m01 = wyz*wx1 * ((y0>=0 && y0<H_ && x1>=0 && x1<W_) ? 1.f : 0.f);
        float m10 = wy1*wxz * ((y1>=0 && y1<H_ && x0>=0 && x0<W_) ? 1.f : 0.f);
        float m11 = wy1*wx1 * ((y1>=0 && y1<H_ && x1>=0 && x1<W_) ? 1.f : 0.f);
        int x0c = min(max(x0,0),W_-1), x1c = min(max(x1,0),W_-1);
        int y0c = min(max(y0,0),H_-1), y1c = min(max(y1,0),H_-1);
        size_t p00 = (size_t)y0c*W_ + x0c, p01 = (size_t)y0c*W_ + x1c;
        size_t p10 = (size_t)y1c*W_ + x0c, p11 = (size_t)y1c*W_ + x1c;
        #pragma unroll
        for (int e = 0; e < 8; ++e) {
            int d = dg + e;
            const float* kp = kbase + (size_t)d*HW_;
            const float* vp = vbase + (size_t)d*HW_;
            k_s[d][tok] = m00*kp[p00] + m01*kp[p01] + m10*kp[p10] + m11*kp[p11];
            v_s[d][tok] = m00*vp[p00] + m01*vp[p01] + m10*vp[p10] + m11*vp[p11];
        }
    }
    __syncthreads();

    const float scale = 0.17677669529663687f;
    {   // S = q.kT * scale + rpb
        int qi0 = (t & 15)*4, ki0 = (t >> 4)*4;
        float acc[4][4];
        #pragma unroll
        for (int a=0;a<4;++a)
            #pragma unroll
            for (int c=0;c<4;++c) acc[a][c]=0.f;
        #pragma unroll
        for (int d = 0; d < 32; ++d) {
            float4 qv = *(const float4*)&q_s[d][qi0];
            float4 kv = *(const float4*)&k_s[d][ki0];
            float qa[4]={qv.x,qv.y,qv.z,qv.w}, ka[4]={kv.x,kv.y,kv.z,kv.w};
            #pragma unroll
            for (int a=0;a<4;++a)
                #pragma unroll
                for (int c=0;c<4;++c) acc[a][c] += qa[a]*ka[c];
        }
        #pragma unroll
        for (int a=0;a<4;++a) {
            int qi = qi0+a; int yq = qi>>3, xq = qi&7;
            #pragma unroll
            for (int c=0;c<4;++c) {
                int ki = ki0+c; int yk = ki>>3, xk = ki&7;
                int idx = (yq-yk+7)*15 + (xq-xk+7);
                S[qi][ki] = acc[a][c]*scale + rpb_table[idx*8 + nh];
            }
        }
    }
    __syncthreads();
    {
        int r = t & 63, part = t >> 6;
        float m = -1e30f;
        #pragma unroll
        for (int c = 0; c < 16; ++c) m = fmaxf(m, S[r][part*16+c]);
        red[part][r] = m;
    }
    __syncthreads();
    if (t < 64) rowm[t] = fmaxf(fmaxf(red[0][t],red[1][t]),fmaxf(red[2][t],red[3][t]));
    __syncthreads();
    {
        int r = t & 63, part = t >> 6;
        float m = rowm[r], s = 0.f;
        #pragma unroll
        for (int c = 0; c < 16; ++c) {
            float e = __expf(S[r][part*16+c] - m);
            S[r][part*16+c] = e;
            s += e;
        }
        red[part][r] = s;
    }
    __syncthreads();
    if (t < 64) rowinv[t] = 1.f / (red[0][t]+red[1][t]+red[2][t]+red[3][t]);
    __syncthreads();
    {   // out[q][d] -> write bf16 hi/lo at [p][c] (c = nh*32+d)
        int qi0 = (t & 15)*4, d0 = (t >> 4)*2;
        float acc[4][2];
        #pragma unroll
        for (int a=0;a<4;++a) { acc[a][0]=0.f; acc[a][1]=0.f; }
        for (int k = 0; k < 64; ++k) {
            float v0 = v_s[d0][k], v1 = v_s[d0+1][k];
            #pragma unroll
            for (int a=0;a<4;++a) {
                float pv = S[qi0+a][k];
                acc[a][0] += pv*v0; acc[a][1] += pv*v1;
            }
        }
        #pragma unroll
        for (int a=0;a<4;++a) {
            int qi = qi0+a;
            float inv = rowinv[qi];
            int i = qi>>3, j = qi&7;
            size_t p = (size_t)(wy*8+i)*W_ + wx*8 + j;
            float v0 = acc[a][0]*inv, v1 = acc[a][1]*inv;
            ushort_t h0 = bf16_rtn(v0); ushort_t l0 = bf16_rtn(v0 - bf16_tof(h0));
            ushort_t h1 = bf16_rtn(v1); ushort_t l1 = bf16_rtn(v1 - bf16_tof(h1));
            size_t off = p*256 + nh*32 + d0;
            *(uint_t*)(ath + off) = (uint_t)h0 | ((uint_t)h1 << 16);
            *(uint_t*)(atl + off) = (uint_t)l0 | ((uint_t)l1 << 16);
        }
    }
}

extern "C" void kernel_launch(void* const* d_in, const int* in_sizes, int n_in,
                              void* d_out, int out_size, void* d_ws, size_t ws_size,
                              hipStream_t stream) {
    const float* x       = (const float*)d_in[0];
    const float* qkv_w   = (const float*)d_in[1];
    const float* qkv_b   = (const float*)d_in[2];
    const float* bias_w  = (const float*)d_in[3];
    const float* bias_b  = (const float*)d_in[4];
    const float* scale_w = (const float*)d_in[5];
    const float* scale_b = (const float*)d_in[6];
    const float* proj_w  = (const float*)d_in[7];
    const float* proj_b  = (const float*)d_in[8];
    const float* rpb     = (const float*)d_in[9];
    float* out = (float*)d_out;

    // workspace layout (~69 MB): at_* aliases xt_* (xt dead after qkv GEMM)
    char* ws = (char*)d_ws;
    float*    xp     = (float*)ws;                          ws += 524288*4;
    float*    params = (float*)ws;                          ws += 65536*4;
    ushort_t* wq_h   = (ushort_t*)ws;                       ws += 768*256*2;
    ushort_t* wq_l   = (ushort_t*)ws;                       ws += 768*256*2;
    ushort_t* wp_h   = (ushort_t*)ws;                       ws += 256*256*2;
    ushort_t* wp_l   = (ushort_t*)ws;                       ws += 256*256*2;
    ushort_t* xt_h   = (ushort_t*)ws;                       ws += (size_t)HW_*256*2;
    ushort_t* xt_l   = (ushort_t*)ws;                       ws += (size_t)HW_*256*2;
    float*    qkvbuf = (float*)ws;                          // 768*HW_*4 = 50 MB

    wconv_kernel<<<dim3(192), 256, 0, stream>>>(qkv_w, wq_h, wq_l, 768*256/4);
    wconv_kernel<<<dim3(64),  256, 0, stream>>>(proj_w, wp_h, wp_l, 256*256/4);
    pool_kernel  <<<dim3(B_*C_),    256, 0, stream>>>(x, xp);
    params_kernel<<<dim3(B_*NWIN_), 256, 0, stream>>>(xp, bias_w, bias_b, scale_w, scale_b, params);

    for (int b = 0; b < B_; ++b) {
        const float* xb = x + (size_t)b*C_*HW_;
        transpose_split_kernel<<<dim3(256, 4), 256, 0, stream>>>(xb, xt_h, xt_l);
        mgemm_kernel<<<dim3(128, 6), 256, 0, stream>>>(wq_h, wq_l, xt_h, xt_l, qkv_b, qkvbuf);
        attn_kernel <<<dim3(NH_*NWIN_), 256, 0, stream>>>(qkvbuf, params, rpb, xt_h, xt_l, b);
        mgemm_kernel<<<dim3(128, 2), 256, 0, stream>>>(wp_h, wp_l, xt_h, xt_l, proj_b, out + (size_t)b*C_*HW_);
    }
}

// Round 5
// 799.794 us; speedup vs baseline: 1.7099x; 1.1087x over previous
//
#include <hip/hip_runtime.h>

#define B_ 8
#define C_ 256
#define H_ 128
#define W_ 128
#define NH_ 8
#define WS_ 8
#define HD_ 32
#define WN_ 16
#define NWIN_ 256
#define HW_ 16384

typedef unsigned short ushort_t;
typedef unsigned int uint_t;
typedef __attribute__((ext_vector_type(8))) short short8;
typedef __attribute__((ext_vector_type(4))) float f32x4;

__device__ __forceinline__ ushort_t bf16_rtn(float x) {
    uint_t u = __float_as_uint(x);
    return (ushort_t)((u + 0x7FFFu + ((u >> 16) & 1u)) >> 16);
}
__device__ __forceinline__ float bf16_tof(ushort_t h) {
    return __uint_as_float(((uint_t)h) << 16);
}

// ---------- weight f32 -> bf16 hi/lo split (same [o][c] layout) ----------
__global__ __launch_bounds__(256) void wconv_kernel(const float* __restrict__ w,
                            ushort_t* __restrict__ wh, ushort_t* __restrict__ wl, int n4) {
    int i = blockIdx.x*256 + threadIdx.x;
    if (i >= n4) return;
    float4 v = ((const float4*)w)[i];
    float vv[4] = {v.x, v.y, v.z, v.w};
    ushort_t h[4], l[4];
    #pragma unroll
    for (int e = 0; e < 4; ++e) {
        h[e] = bf16_rtn(vv[e]);
        l[e] = bf16_rtn(vv[e] - bf16_tof(h[e]));
    }
    ((uint2*)wh)[i] = make_uint2((uint_t)h[0]|((uint_t)h[1]<<16), (uint_t)h[2]|((uint_t)h[3]<<16));
    ((uint2*)wl)[i] = make_uint2((uint_t)l[0]|((uint_t)l[1]<<16), (uint_t)l[2]|((uint_t)l[3]<<16));
}

// ---------- transpose + split + window-partial-pool, all images ----------
// x[b][c][p] f32 -> xt_h/xt_l[b][p][c] bf16 ; xpart[b][c][h][wxg] = sum_j x
__global__ __launch_bounds__(256) void transpose_split_kernel(const float* __restrict__ x,
                            ushort_t* __restrict__ th, ushort_t* __restrict__ tl,
                            float* __restrict__ xpart) {
    __shared__ float tile[64][65];
    int b = blockIdx.z;
    int p0 = blockIdx.x * 64, c0 = blockIdx.y * 64;
    const float* xsrc = x + (size_t)b*C_*HW_;
    int t = threadIdx.x;
    #pragma unroll
    for (int r = 0; r < 4; ++r) {
        int task = t + r*256;
        int cl = task >> 4, p4 = (task & 15) * 4;
        float4 v = *(const float4*)(xsrc + (size_t)(c0+cl)*HW_ + p0 + p4);
        tile[cl][p4+0] = v.x; tile[cl][p4+1] = v.y; tile[cl][p4+2] = v.z; tile[cl][p4+3] = v.w;
    }
    __syncthreads();
    {   // window partial sums over j (this block covers h = p0>>7, w in [wbase*8, +64))
        int h = blockIdx.x >> 1, wbase = (blockIdx.x & 1) * 8;
        #pragma unroll
        for (int r = 0; r < 2; ++r) {
            int task = t + r*256;
            int cl = task >> 3, wx = task & 7;
            float s = 0.f;
            #pragma unroll
            for (int j = 0; j < 8; ++j) s += tile[cl][wx*8+j];
            xpart[(((size_t)b*256 + c0+cl)*128 + h)*16 + wbase + wx] = s;
        }
    }
    ushort_t* thb = th + (size_t)b*HW_*256;
    ushort_t* tlb = tl + (size_t)b*HW_*256;
    #pragma unroll
    for (int r = 0; r < 2; ++r) {
        int task = t + r*256;
        int pl = task >> 3, cb = (task & 7) * 8;
        ushort_t h[8], l[8];
        #pragma unroll
        for (int e = 0; e < 8; ++e) {
            float v = tile[cb+e][pl];
            h[e] = bf16_rtn(v);
            l[e] = bf16_rtn(v - bf16_tof(h[e]));
        }
        uint4 Hh, Ll;
        Hh.x = (uint_t)h[0]|((uint_t)h[1]<<16); Hh.y = (uint_t)h[2]|((uint_t)h[3]<<16);
        Hh.z = (uint_t)h[4]|((uint_t)h[5]<<16); Hh.w = (uint_t)h[6]|((uint_t)h[7]<<16);
        Ll.x = (uint_t)l[0]|((uint_t)l[1]<<16); Ll.y = (uint_t)l[2]|((uint_t)l[3]<<16);
        Ll.z = (uint_t)l[4]|((uint_t)l[5]<<16); Ll.w = (uint_t)l[6]|((uint_t)l[7]<<16);
        *(uint4*)(thb + (size_t)(p0+pl)*256 + c0 + cb) = Hh;
        *(uint4*)(tlb + (size_t)(p0+pl)*256 + c0 + cb) = Ll;
    }
}

// ---------- finish pool: mean over h-partials + leaky relu ----------
__global__ __launch_bounds__(256) void pool2_kernel(const float* __restrict__ xpart, float* __restrict__ xp) {
    int bc = blockIdx.x;               // b*256 + c
    int t = threadIdx.x;               // win = wy*16 + wxg
    int wy = t >> 4, wxg = t & 15;
    const float* src = xpart + (size_t)bc*2048;
    float s = 0.f;
    #pragma unroll
    for (int i = 0; i < 8; ++i) s += src[(wy*8+i)*16 + wxg];
    s *= (1.f/64.f);
    xp[(size_t)bc*256 + t] = s > 0.f ? s : 0.01f*s;
}

// ---------- per-window sampling params {ox, oy, sx, sy} ----------
__global__ __launch_bounds__(256) void params_kernel(const float* __restrict__ xp,
                              const float* __restrict__ bias_w, const float* __restrict__ bias_b,
                              const float* __restrict__ scale_w, const float* __restrict__ scale_b,
                              float* __restrict__ params) {
    __shared__ float xs[256];
    int blk = blockIdx.x;
    int b = blk >> 8, win = blk & 255;
    int t = threadIdx.x;
    xs[t] = xp[((size_t)(b*256 + t))*256 + win];
    __syncthreads();
    if (t < 32) {
        int which = t >> 4;
        int o = t & 15;
        const float* Wm = which ? scale_w : bias_w;
        float acc = which ? scale_b[o] : bias_b[o];
        for (int c = 0; c < 256; ++c) acc += Wm[o*256 + c] * xs[c];
        int nh = o >> 1, comp = o & 1;
        int n = b*8 + nh;
        float v = which ? acc : 3.96875f * acc;
        params[((size_t)(n*256 + win))*4 + which*2 + comp] = v;
    }
}

// ---------- MFMA split-bf16 GEMM, channel-last epilogue ----------
// wh/wl: [768][256] ; xh/xl: [16384][256] (one image) ; out: [16384][768] f32
__global__ __launch_bounds__(256) void mgemm_qkvt_kernel(const ushort_t* __restrict__ wh, const ushort_t* __restrict__ wl,
                            const ushort_t* __restrict__ xh, const ushort_t* __restrict__ xl,
                            const float* __restrict__ bias, float* __restrict__ out) {
    __shared__ __align__(16) uint4 smem[4096];   // 64 KB
    uint4* Ah = smem;        uint4* Al = smem + 1024;
    uint4* Bh = smem + 2048; uint4* Bl = smem + 3072;
    int o0 = blockIdx.x * 128, p0 = blockIdx.y * 128;
    int t = threadIdx.x;
    int lane = t & 63, wid = t >> 6;
    int wm = wid >> 1, wn = wid & 1;
    int q = lane >> 4, rl = lane & 15;

    f32x4 acc[4][4];
    #pragma unroll
    for (int f = 0; f < 4; ++f)
        #pragma unroll
        for (int g = 0; g < 4; ++g)
            acc[f][g] = (f32x4){0.f, 0.f, 0.f, 0.f};

    int srow = t >> 1, shalf = t & 1;
    int sw = srow & 7;

    for (int ks = 0; ks < 4; ++ks) {
        int c0 = ks * 64;
        __syncthreads();
        {
            const uint4* a_h = (const uint4*)(wh + (size_t)(o0+srow)*256 + c0);
            const uint4* a_l = (const uint4*)(wl + (size_t)(o0+srow)*256 + c0);
            const uint4* b_h = (const uint4*)(xh + (size_t)(p0+srow)*256 + c0);
            const uint4* b_l = (const uint4*)(xl + (size_t)(p0+srow)*256 + c0);
            #pragma unroll
            for (int jj = 0; jj < 4; ++jj) {
                int u = shalf*4 + jj;
                int d = srow*8 + (u ^ sw);
                Ah[d] = a_h[u]; Al[d] = a_l[u];
                Bh[d] = b_h[u]; Bl[d] = b_l[u];
            }
        }
        __syncthreads();
        #pragma unroll
        for (int kk = 0; kk < 2; ++kk) {
            short8 afh[4], afl[4], bfh[4], bfl[4];
            #pragma unroll
            for (int f = 0; f < 4; ++f) {
                int row = wm*64 + f*16 + rl;
                int u = (kk*4 + q) ^ (row & 7);
                afh[f] = __builtin_bit_cast(short8, Ah[row*8 + u]);
                afl[f] = __builtin_bit_cast(short8, Al[row*8 + u]);
            }
            #pragma unroll
            for (int g = 0; g < 4; ++g) {
                int row = wn*64 + g*16 + rl;
                int u = (kk*4 + q) ^ (row & 7);
                bfh[g] = __builtin_bit_cast(short8, Bh[row*8 + u]);
                bfl[g] = __builtin_bit_cast(short8, Bl[row*8 + u]);
            }
            #pragma unroll
            for (int f = 0; f < 4; ++f)
                #pragma unroll
                for (int g = 0; g < 4; ++g) {
                    acc[f][g] = __builtin_amdgcn_mfma_f32_16x16x32_bf16(afh[f], bfh[g], acc[f][g], 0, 0, 0);
                    acc[f][g] = __builtin_amdgcn_mfma_f32_16x16x32_bf16(afh[f], bfl[g], acc[f][g], 0, 0, 0);
                    acc[f][g] = __builtin_amdgcn_mfma_f32_16x16x32_bf16(afl[f], bfh[g], acc[f][g], 0, 0, 0);
                }
        }
    }
    // channel-last epilogue: LDS transpose in 2 passes of 64 o-rows
    float* tb = (float*)smem;   // [64][129]
    int pl = t >> 1, half = t & 1;
    #pragma unroll
    for (int pass = 0; pass < 2; ++pass) {
        __syncthreads();
        if (wm == pass) {
            #pragma unroll
            for (int f = 0; f < 4; ++f)
                #pragma unroll
                for (int g = 0; g < 4; ++g)
                    #pragma unroll
                    for (int r = 0; r < 4; ++r)
                        tb[(f*16 + q*4 + r)*129 + wn*64 + g*16 + rl] = acc[f][g][r];
        }
        __syncthreads();
        {
            float vals[32];
            #pragma unroll
            for (int i2 = 0; i2 < 32; ++i2) vals[i2] = tb[(half*32 + i2)*129 + pl];
            int obase = o0 + pass*64 + half*32;
            float* dst = out + (size_t)(p0+pl)*768 + obase;
            #pragma unroll
            for (int u = 0; u < 8; ++u) {
                float4 bb = *(const float4*)&bias[obase + u*4];
                float4 vv = {vals[u*4]+bb.x, vals[u*4+1]+bb.y, vals[u*4+2]+bb.z, vals[u*4+3]+bb.w};
                *(float4*)(dst + u*4) = vv;
            }
        }
    }
}

// ---------- MFMA split-bf16 GEMM for proj, standard [o][p] epilogue, z-batched ----------
__global__ __launch_bounds__(256) void mgemm_proj_kernel(const ushort_t* __restrict__ wh, const ushort_t* __restrict__ wl,
                            const ushort_t* __restrict__ ah, const ushort_t* __restrict__ al,
                            const float* __restrict__ bias, float* __restrict__ out) {
    __shared__ __align__(16) uint4 smem[4096];
    uint4* Ah = smem;        uint4* Al = smem + 1024;
    uint4* Bh = smem + 2048; uint4* Bl = smem + 3072;
    int zb = blockIdx.z;
    const ushort_t* xh = ah + (size_t)zb*HW_*256;
    const ushort_t* xl = al + (size_t)zb*HW_*256;
    float* outb = out + (size_t)zb*C_*HW_;
    int o0 = blockIdx.x * 128, p0 = blockIdx.y * 128;
    int t = threadIdx.x;
    int lane = t & 63, wid = t >> 6;
    int wm = wid >> 1, wn = wid & 1;
    int q = lane >> 4, rl = lane & 15;

    f32x4 acc[4][4];
    #pragma unroll
    for (int f = 0; f < 4; ++f)
        #pragma unroll
        for (int g = 0; g < 4; ++g)
            acc[f][g] = (f32x4){0.f, 0.f, 0.f, 0.f};

    int srow = t >> 1, shalf = t & 1;
    int sw = srow & 7;

    for (int ks = 0; ks < 4; ++ks) {
        int c0 = ks * 64;
        __syncthreads();
        {
            const uint4* a_h = (const uint4*)(wh + (size_t)(o0+srow)*256 + c0);
            const uint4* a_l = (const uint4*)(wl + (size_t)(o0+srow)*256 + c0);
            const uint4* b_h = (const uint4*)(xh + (size_t)(p0+srow)*256 + c0);
            const uint4* b_l = (const uint4*)(xl + (size_t)(p0+srow)*256 + c0);
            #pragma unroll
            for (int jj = 0; jj < 4; ++jj) {
                int u = shalf*4 + jj;
                int d = srow*8 + (u ^ sw);
                Ah[d] = a_h[u]; Al[d] = a_l[u];
                Bh[d] = b_h[u]; Bl[d] = b_l[u];
            }
        }
        __syncthreads();
        #pragma unroll
        for (int kk = 0; kk < 2; ++kk) {
            short8 afh[4], afl[4], bfh[4], bfl[4];
            #pragma unroll
            for (int f = 0; f < 4; ++f) {
                int row = wm*64 + f*16 + rl;
                int u = (kk*4 + q) ^ (row & 7);
                afh[f] = __builtin_bit_cast(short8, Ah[row*8 + u]);
                afl[f] = __builtin_bit_cast(short8, Al[row*8 + u]);
            }
            #pragma unroll
            for (int g = 0; g < 4; ++g) {
                int row = wn*64 + g*16 + rl;
                int u = (kk*4 + q) ^ (row & 7);
                bfh[g] = __builtin_bit_cast(short8, Bh[row*8 + u]);
                bfl[g] = __builtin_bit_cast(short8, Bl[row*8 + u]);
            }
            #pragma unroll
            for (int f = 0; f < 4; ++f)
                #pragma unroll
                for (int g = 0; g < 4; ++g) {
                    acc[f][g] = __builtin_amdgcn_mfma_f32_16x16x32_bf16(afh[f], bfh[g], acc[f][g], 0, 0, 0);
                    acc[f][g] = __builtin_amdgcn_mfma_f32_16x16x32_bf16(afh[f], bfl[g], acc[f][g], 0, 0, 0);
                    acc[f][g] = __builtin_amdgcn_mfma_f32_16x16x32_bf16(afl[f], bfh[g], acc[f][g], 0, 0, 0);
                }
        }
    }
    #pragma unroll
    for (int f = 0; f < 4; ++f) {
        float4 bb = *(const float4*)&bias[o0 + wm*64 + f*16 + q*4];
        float bbv[4] = {bb.x, bb.y, bb.z, bb.w};
        #pragma unroll
        for (int g = 0; g < 4; ++g) {
            int p = p0 + wn*64 + g*16 + rl;
            #pragma unroll
            for (int r = 0; r < 4; ++r) {
                int o = o0 + wm*64 + f*16 + q*4 + r;
                outb[(size_t)o*HW_ + p] = acc[f][g][r] + bbv[r];
            }
        }
    }
}

// ---------- fused bilinear sampling + windowed attention (one image, channel-last qkv) ----------
__global__ __launch_bounds__(256) void attn_kernel(const float* __restrict__ qkvt,
                            const float* __restrict__ params_,
                            const float* __restrict__ rpb_table,
                            ushort_t* __restrict__ at_h, ushort_t* __restrict__ at_l, int b) {
    __shared__ __align__(16) float q_s[32][68];
    __shared__ __align__(16) float k_s[32][68];
    __shared__ __align__(16) float v_s[32][68];
    __shared__ __align__(16) float S[64][65];
    __shared__ float red[4][64];
    __shared__ float rowm[64], rowinv[64];

    int blk = blockIdx.x;
    int nh = blk >> 8, win = blk & 255;
    int wy = win >> 4, wx = win & 15;
    int t = threadIdx.x;

    const float* pp = params_ + ((size_t)((b*8 + nh)*256 + win))*4;
    float ox = pp[0], oy = pp[1], sx = pp[2], sy = pp[3];

    ushort_t* ath = at_h + (size_t)b*HW_*256;
    ushort_t* atl = at_l + (size_t)b*HW_*256;

    {   // load q + bilinear-gather k,v into LDS [d][tok]; channel-last source
        int tok = t >> 2, d4 = (t & 3) * 4;
        int i = tok >> 3, j = tok & 7;
        int h = wy*8 + i, w = wx*8 + j;
        size_t p_q = (size_t)h*W_ + w;
        {
            const float* pq = qkvt + p_q*768 + nh*32 + d4;
            float4 qa = *(const float4*)pq;
            float4 qb = *(const float4*)(pq + 16);
            q_s[d4+0][tok] = qa.x; q_s[d4+1][tok] = qa.y; q_s[d4+2][tok] = qa.z; q_s[d4+3][tok] = qa.w;
            q_s[16+d4+0][tok] = qb.x; q_s[16+d4+1][tok] = qb.y; q_s[16+d4+2][tok] = qb.z; q_s[16+d4+3][tok] = qb.w;
        }
        float gx = (float)w + ((float)j - 3.5f)*sx + ox;
        float gy = (float)h + ((float)i - 3.5f)*sy + oy;
        float x0f = floorf(gx), y0f = floorf(gy);
        int x0 = (int)x0f, y0 = (int)y0f;
        float wx1 = gx - x0f, wy1 = gy - y0f;
        float wxz = 1.f - wx1, wyz = 1.f - wy1;
        int x1 = x0 + 1, y1 = y0 + 1;
        float m00 = wyz*wxz * ((y0>=0 && y0<H_ && x0>=0 && x0<W_) ? 1.f : 0.f);
        float m01 = wyz*wx1 * ((y0>=0 && y0<H_ && x1>=0 && x1<W_) ? 1.f : 0.f);
        float m10 = wy1*wxz * ((y1>=0 && y1<H_ && x0>=0 && x0<W_) ? 1.f : 0.f);
        float m11 = wy1*wx1 * ((y1>=0 && y1<H_ && x1>=0 && x1<W_) ? 1.f : 0.f);
        int x0c = min(max(x0,0),W_-1), x1c = min(max(x1,0),W_-1);
        int y0c = min(max(y0,0),H_-1), y1c = min(max(y1,0),H_-1);
        size_t p00 = (size_t)y0c*W_ + x0c, p01 = (size_t)y0c*W_ + x1c;
        size_t p10 = (size_t)y1c*W_ + x0c, p11 = (size_t)y1c*W_ + x1c;
        float kacc[8], vacc[8];
        #pragma unroll
        for (int e = 0; e < 8; ++e) { kacc[e] = 0.f; vacc[e] = 0.f; }
        int colk = 256 + nh*32 + d4;
        int colv = 512 + nh*32 + d4;
        #define CORNER(PIX, WGT) { \
            const float* cp = qkvt + (PIX)*768; \
            float4 ka = *(const float4*)(cp + colk); \
            float4 kb = *(const float4*)(cp + colk + 16); \
            float4 va = *(const float4*)(cp + colv); \
            float4 vb = *(const float4*)(cp + colv + 16); \
            kacc[0] += (WGT)*ka.x; kacc[1] += (WGT)*ka.y; kacc[2] += (WGT)*ka.z; kacc[3] += (WGT)*ka.w; \
            kacc[4] += (WGT)*kb.x; kacc[5] += (WGT)*kb.y; kacc[6] += (WGT)*kb.z; kacc[7] += (WGT)*kb.w; \
            vacc[0] += (WGT)*va.x; vacc[1] += (WGT)*va.y; vacc[2] += (WGT)*va.z; vacc[3] += (WGT)*va.w; \
            vacc[4] += (WGT)*vb.x; vacc[5] += (WGT)*vb.y; vacc[6] += (WGT)*vb.z; vacc[7] += (WGT)*vb.w; }
        CORNER(p00, m00)
        CORNER(p01, m01)
        CORNER(p10, m10)
        CORNER(p11, m11)
        #undef CORNER
        #pragma unroll
        for (int e = 0; e < 4; ++e) {
            k_s[d4+e][tok] = kacc[e];    k_s[16+d4+e][tok] = kacc[4+e];
            v_s[d4+e][tok] = vacc[e];    v_s[16+d4+e][tok] = vacc[4+e];
        }
    }
    __syncthreads();

    const float scale = 0.17677669529663687f;
    {   // S = q.kT * scale + rpb
        int qi0 = (t & 15)*4, ki0 = (t >> 4)*4;
        float acc[4][4];
        #pragma unroll
        for (int a=0;a<4;++a)
            #pragma unroll
            for (int c=0;c<4;++c) acc[a][c]=0.f;
        #pragma unroll
        for (int d = 0; d < 32; ++d) {
            float4 qv = *(const float4*)&q_s[d][qi0];
            float4 kv = *(const float4*)&k_s[d][ki0];
            float qa[4]={qv.x,qv.y,qv.z,qv.w}, ka[4]={kv.x,kv.y,kv.z,kv.w};
            #pragma unroll
            for (int a=0;a<4;++a)
                #pragma unroll
                for (int c=0;c<4;++c) acc[a][c] += qa[a]*ka[c];
        }
        #pragma unroll
        for (int a=0;a<4;++a) {
            int qi = qi0+a; int yq = qi>>3, xq = qi&7;
            #pragma unroll
            for (int c=0;c<4;++c) {
                int ki = ki0+c; int yk = ki>>3, xk = ki&7;
                int idx = (yq-yk+7)*15 + (xq-xk+7);
                S[qi][ki] = acc[a][c]*scale + rpb_table[idx*8 + nh];
            }
        }
    }
    __syncthreads();
    {
        int r = t & 63, part = t >> 6;
        float m = -1e30f;
        #pragma unroll
        for (int c = 0; c < 16; ++c) m = fmaxf(m, S[r][part*16+c]);
        red[part][r] = m;
    }
    __syncthreads();
    if (t < 64) rowm[t] = fmaxf(fmaxf(red[0][t],red[1][t]),fmaxf(red[2][t],red[3][t]));
    __syncthreads();
    {
        int r = t & 63, part = t >> 6;
        float m = rowm[r], s = 0.f;
        #pragma unroll
        for (int c = 0; c < 16; ++c) {
            float e = __expf(S[r][part*16+c] - m);
            S[r][part*16+c] = e;
            s += e;
        }
        red[part][r] = s;
    }
    __syncthreads();
    if (t < 64) rowinv[t] = 1.f / (red[0][t]+red[1][t]+red[2][t]+red[3][t]);
    __syncthreads();
    {   // PV
        int qi0 = (t & 15)*4, d0 = (t >> 4)*2;
        float acc[4][2];
        #pragma unroll
        for (int a=0;a<4;++a) { acc[a][0]=0.f; acc[a][1]=0.f; }
        for (int k = 0; k < 64; ++k) {
            float v0 = v_s[d0][k], v1 = v_s[d0+1][k];
            #pragma unroll
            for (int a=0;a<4;++a) {
                float pv = S[qi0+a][k];
                acc[a][0] += pv*v0; acc[a][1] += pv*v1;
            }
        }
        __syncthreads();  // all P reads done; S reusable
        #pragma unroll
        for (int a=0;a<4;++a) {
            int qi = qi0+a;
            float inv = rowinv[qi];
            S[qi][d0]   = acc[a][0]*inv;
            S[qi][d0+1] = acc[a][1]*inv;
        }
    }
    __syncthreads();
    {   // coalesced bf16 hi/lo output: [p][256] at col nh*32..+31  (64 pix x 8 ch per thread)
        int pix = t >> 2, cq = (t & 3) * 8;
        int i2 = pix >> 3, j2 = pix & 7;
        size_t prow = (size_t)(wy*8+i2)*W_ + wx*8 + j2;
        ushort_t hh[8], ll[8];
        #pragma unroll
        for (int e = 0; e < 8; ++e) {
            float f = S[pix][cq+e];
            hh[e] = bf16_rtn(f);
            ll[e] = bf16_rtn(f - bf16_tof(hh[e]));
        }
        uint4 Hv, Lv;
        Hv.x = (uint_t)hh[0]|((uint_t)hh[1]<<16); Hv.y = (uint_t)hh[2]|((uint_t)hh[3]<<16);
        Hv.z = (uint_t)hh[4]|((uint_t)hh[5]<<16); Hv.w = (uint_t)hh[6]|((uint_t)hh[7]<<16);
        Lv.x = (uint_t)ll[0]|((uint_t)ll[1]<<16); Lv.y = (uint_t)ll[2]|((uint_t)ll[3]<<16);
        Lv.z = (uint_t)ll[4]|((uint_t)ll[5]<<16); Lv.w = (uint_t)ll[6]|((uint_t)ll[7]<<16);
        size_t off = prow*256 + nh*32 + cq;
        *(uint4*)(ath + off) = Hv;
        *(uint4*)(atl + off) = Lv;
    }
}

extern "C" void kernel_launch(void* const* d_in, const int* in_sizes, int n_in,
                              void* d_out, int out_size, void* d_ws, size_t ws_size,
                              hipStream_t stream) {
    const float* x       = (const float*)d_in[0];
    const float* qkv_w   = (const float*)d_in[1];
    const float* qkv_b   = (const float*)d_in[2];
    const float* bias_w  = (const float*)d_in[3];
    const float* bias_b  = (const float*)d_in[4];
    const float* scale_w = (const float*)d_in[5];
    const float* scale_b = (const float*)d_in[6];
    const float* proj_w  = (const float*)d_in[7];
    const float* proj_b  = (const float*)d_in[8];
    const float* rpb     = (const float*)d_in[9];
    float* out = (float*)d_out;

    // workspace (~338 MB of 512 MiB)
    char* ws = (char*)d_ws;
    float*    xp     = (float*)ws;     ws += (size_t)524288*4;
    float*    params = (float*)ws;     ws += (size_t)65536*4;
    float*    xpart  = (float*)ws;     ws += (size_t)4194304*4;
    ushort_t* wq_h   = (ushort_t*)ws;  ws += (size_t)768*256*2;
    ushort_t* wq_l   = (ushort_t*)ws;  ws += (size_t)768*256*2;
    ushort_t* wp_h   = (ushort_t*)ws;  ws += (size_t)256*256*2;
    ushort_t* wp_l   = (ushort_t*)ws;  ws += (size_t)256*256*2;
    ushort_t* xt_h   = (ushort_t*)ws;  ws += (size_t)B_*HW_*256*2;
    ushort_t* xt_l   = (ushort_t*)ws;  ws += (size_t)B_*HW_*256*2;
    ushort_t* at_h   = (ushort_t*)ws;  ws += (size_t)B_*HW_*256*2;
    ushort_t* at_l   = (ushort_t*)ws;  ws += (size_t)B_*HW_*256*2;
    float*    qkvt   = (float*)ws;     // 16384*768*4 = 50 MB

    wconv_kernel<<<dim3(192), 256, 0, stream>>>(qkv_w, wq_h, wq_l, 768*256/4);
    wconv_kernel<<<dim3(64),  256, 0, stream>>>(proj_w, wp_h, wp_l, 256*256/4);
    transpose_split_kernel<<<dim3(256, 4, B_), 256, 0, stream>>>(x, xt_h, xt_l, xpart);
    pool2_kernel <<<dim3(B_*C_), 256, 0, stream>>>(xpart, xp);
    params_kernel<<<dim3(B_*NWIN_), 256, 0, stream>>>(xp, bias_w, bias_b, scale_w, scale_b, params);

    for (int b = 0; b < B_; ++b) {
        mgemm_qkvt_kernel<<<dim3(6, 128), 256, 0, stream>>>(wq_h, wq_l,
            xt_h + (size_t)b*HW_*256, xt_l + (size_t)b*HW_*256, qkv_b, qkvt);
        attn_kernel<<<dim3(NH_*NWIN_), 256, 0, stream>>>(qkvt, params, rpb, at_h, at_l, b);
    }
    mgemm_proj_kernel<<<dim3(2, 128, B_), 256, 0, stream>>>(wp_h, wp_l, at_h, at_l, proj_b, out);
}

// Round 6
// 484.555 us; speedup vs baseline: 2.8224x; 1.6506x over previous
//
#include <hip/hip_runtime.h>

#define B_ 8
#define C_ 256
#define H_ 128
#define W_ 128
#define NH_ 8
#define WS_ 8
#define HD_ 32
#define WN_ 16
#define NWIN_ 256
#define HW_ 16384

typedef unsigned short ushort_t;
typedef unsigned int uint_t;
typedef __attribute__((ext_vector_type(8))) short short8;
typedef __attribute__((ext_vector_type(4))) float f32x4;

__device__ __forceinline__ ushort_t bf16_rtn(float x) {
    uint_t u = __float_as_uint(x);
    return (ushort_t)((u + 0x7FFFu + ((u >> 16) & 1u)) >> 16);
}
__device__ __forceinline__ uint_t bfpack(float a, float b) {
    return (uint_t)bf16_rtn(a) | ((uint_t)bf16_rtn(b) << 16);
}
__device__ __forceinline__ void bf8_unpack(uint4 u, float* f) {
    f[0]=__uint_as_float((u.x&0xffffu)<<16); f[1]=__uint_as_float(u.x&0xffff0000u);
    f[2]=__uint_as_float((u.y&0xffffu)<<16); f[3]=__uint_as_float(u.y&0xffff0000u);
    f[4]=__uint_as_float((u.z&0xffffu)<<16); f[5]=__uint_as_float(u.z&0xffff0000u);
    f[6]=__uint_as_float((u.w&0xffffu)<<16); f[7]=__uint_as_float(u.w&0xffff0000u);
}

// ---------- weight f32 -> bf16 ----------
__global__ __launch_bounds__(256) void wconv_kernel(const float* __restrict__ w,
                            ushort_t* __restrict__ wh, int n4) {
    int i = blockIdx.x*256 + threadIdx.x;
    if (i >= n4) return;
    float4 v = ((const float4*)w)[i];
    ((uint2*)wh)[i] = make_uint2(bfpack(v.x, v.y), bfpack(v.z, v.w));
}

// ---------- transpose + bf16 + window-partial-pool, all images ----------
// x[b][c][p] f32 -> xt[b][p][c] bf16 ; xpart[b][c][h][wxg] = sum_j x
__global__ __launch_bounds__(256) void transpose_split_kernel(const float* __restrict__ x,
                            ushort_t* __restrict__ th, float* __restrict__ xpart) {
    __shared__ float tile[64][65];
    int b = blockIdx.z;
    int p0 = blockIdx.x * 64, c0 = blockIdx.y * 64;
    const float* xsrc = x + (size_t)b*C_*HW_;
    int t = threadIdx.x;
    #pragma unroll
    for (int r = 0; r < 4; ++r) {
        int task = t + r*256;
        int cl = task >> 4, p4 = (task & 15) * 4;
        float4 v = *(const float4*)(xsrc + (size_t)(c0+cl)*HW_ + p0 + p4);
        tile[cl][p4+0] = v.x; tile[cl][p4+1] = v.y; tile[cl][p4+2] = v.z; tile[cl][p4+3] = v.w;
    }
    __syncthreads();
    {   // window partial sums over j (this block covers h = p0>>7, w in [wbase*8, +64))
        int h = blockIdx.x >> 1, wbase = (blockIdx.x & 1) * 8;
        #pragma unroll
        for (int r = 0; r < 2; ++r) {
            int task = t + r*256;
            int cl = task >> 3, wx = task & 7;
            float s = 0.f;
            #pragma unroll
            for (int j = 0; j < 8; ++j) s += tile[cl][wx*8+j];
            xpart[(((size_t)b*256 + c0+cl)*128 + h)*16 + wbase + wx] = s;
        }
    }
    ushort_t* thb = th + (size_t)b*HW_*256;
    #pragma unroll
    for (int r = 0; r < 2; ++r) {
        int task = t + r*256;
        int pl = task >> 3, cb = (task & 7) * 8;
        uint4 Hh;
        Hh.x = bfpack(tile[cb+0][pl], tile[cb+1][pl]);
        Hh.y = bfpack(tile[cb+2][pl], tile[cb+3][pl]);
        Hh.z = bfpack(tile[cb+4][pl], tile[cb+5][pl]);
        Hh.w = bfpack(tile[cb+6][pl], tile[cb+7][pl]);
        *(uint4*)(thb + (size_t)(p0+pl)*256 + c0 + cb) = Hh;
    }
}

// ---------- finish pool: mean over h-partials + leaky relu ----------
__global__ __launch_bounds__(256) void pool2_kernel(const float* __restrict__ xpart, float* __restrict__ xp) {
    int bc = blockIdx.x;
    int t = threadIdx.x;
    int wy = t >> 4, wxg = t & 15;
    const float* src = xpart + (size_t)bc*2048;
    float s = 0.f;
    #pragma unroll
    for (int i = 0; i < 8; ++i) s += src[(wy*8+i)*16 + wxg];
    s *= (1.f/64.f);
    xp[(size_t)bc*256 + t] = s > 0.f ? s : 0.01f*s;
}

// ---------- per-window sampling params {ox, oy, sx, sy} ----------
__global__ __launch_bounds__(256) void params_kernel(const float* __restrict__ xp,
                              const float* __restrict__ bias_w, const float* __restrict__ bias_b,
                              const float* __restrict__ scale_w, const float* __restrict__ scale_b,
                              float* __restrict__ params) {
    __shared__ float xs[256];
    int blk = blockIdx.x;
    int b = blk >> 8, win = blk & 255;
    int t = threadIdx.x;
    xs[t] = xp[((size_t)(b*256 + t))*256 + win];
    __syncthreads();
    if (t < 32) {
        int which = t >> 4;
        int o = t & 15;
        const float* Wm = which ? scale_w : bias_w;
        float acc = which ? scale_b[o] : bias_b[o];
        for (int c = 0; c < 256; ++c) acc += Wm[o*256 + c] * xs[c];
        int nh = o >> 1, comp = o & 1;
        int n = b*8 + nh;
        float v = which ? acc : 3.96875f * acc;
        params[((size_t)(n*256 + win))*4 + which*2 + comp] = v;
    }
}

// ---------- single-bf16 MFMA GEMM, channel-last bf16 epilogue, z-batched ----------
// wq: [768][256] bf16 ; xt: [B][16384][256] bf16 ; qkvt: [B][16384][768] bf16
__global__ __launch_bounds__(256) void mgemm_qkvt_kernel(const ushort_t* __restrict__ wq,
                            const ushort_t* __restrict__ xt,
                            const float* __restrict__ bias, ushort_t* __restrict__ qkvt) {
    __shared__ __align__(16) uint4 smem[2112];   // 33 KB
    uint4* Ah = smem; uint4* Bh = smem + 1024;
    int zb = blockIdx.z;
    const ushort_t* xh = xt + (size_t)zb*HW_*256;
    ushort_t* outb = qkvt + (size_t)zb*HW_*768;
    int o0 = blockIdx.x * 128, p0 = blockIdx.y * 128;
    int t = threadIdx.x;
    int lane = t & 63, wid = t >> 6;
    int wm = wid >> 1, wn = wid & 1;
    int q = lane >> 4, rl = lane & 15;

    f32x4 acc[4][4];
    #pragma unroll
    for (int f = 0; f < 4; ++f)
        #pragma unroll
        for (int g = 0; g < 4; ++g)
            acc[f][g] = (f32x4){0.f, 0.f, 0.f, 0.f};

    int srow = t >> 1, shalf = t & 1;
    int sw = srow & 7;

    for (int ks = 0; ks < 4; ++ks) {
        int c0 = ks * 64;
        __syncthreads();
        {
            const uint4* a_h = (const uint4*)(wq + (size_t)(o0+srow)*256 + c0);
            const uint4* b_h = (const uint4*)(xh + (size_t)(p0+srow)*256 + c0);
            #pragma unroll
            for (int jj = 0; jj < 4; ++jj) {
                int u = shalf*4 + jj;
                int d = srow*8 + (u ^ sw);
                Ah[d] = a_h[u]; Bh[d] = b_h[u];
            }
        }
        __syncthreads();
        #pragma unroll
        for (int kk = 0; kk < 2; ++kk) {
            short8 afh[4], bfh[4];
            #pragma unroll
            for (int f = 0; f < 4; ++f) {
                int row = wm*64 + f*16 + rl;
                int u = (kk*4 + q) ^ (row & 7);
                afh[f] = __builtin_bit_cast(short8, Ah[row*8 + u]);
            }
            #pragma unroll
            for (int g = 0; g < 4; ++g) {
                int row = wn*64 + g*16 + rl;
                int u = (kk*4 + q) ^ (row & 7);
                bfh[g] = __builtin_bit_cast(short8, Bh[row*8 + u]);
            }
            #pragma unroll
            for (int f = 0; f < 4; ++f)
                #pragma unroll
                for (int g = 0; g < 4; ++g)
                    acc[f][g] = __builtin_amdgcn_mfma_f32_16x16x32_bf16(afh[f], bfh[g], acc[f][g], 0, 0, 0);
        }
    }
    // channel-last bf16 epilogue: LDS transpose in 2 passes of 64 o-rows
    float* tb = (float*)smem;   // [64][129] = 33 KB
    int pl = t >> 1, half = t & 1;
    #pragma unroll
    for (int pass = 0; pass < 2; ++pass) {
        __syncthreads();
        if (wm == pass) {
            #pragma unroll
            for (int f = 0; f < 4; ++f)
                #pragma unroll
                for (int g = 0; g < 4; ++g)
                    #pragma unroll
                    for (int r = 0; r < 4; ++r)
                        tb[(f*16 + q*4 + r)*129 + wn*64 + g*16 + rl] = acc[f][g][r];
        }
        __syncthreads();
        {
            int obase = o0 + pass*64 + half*32;
            ushort_t* dst = outb + (size_t)(p0+pl)*768 + obase;
            #pragma unroll
            for (int u = 0; u < 4; ++u) {
                float v[8];
                #pragma unroll
                for (int e = 0; e < 8; ++e) v[e] = tb[(half*32 + u*8 + e)*129 + pl];
                float4 b0 = *(const float4*)&bias[obase + u*8];
                float4 b1 = *(const float4*)&bias[obase + u*8 + 4];
                uint4 Hv;
                Hv.x = bfpack(v[0]+b0.x, v[1]+b0.y);
                Hv.y = bfpack(v[2]+b0.z, v[3]+b0.w);
                Hv.z = bfpack(v[4]+b1.x, v[5]+b1.y);
                Hv.w = bfpack(v[6]+b1.z, v[7]+b1.w);
                ((uint4*)dst)[u] = Hv;
            }
        }
    }
}

// ---------- single-bf16 MFMA GEMM for proj, [o][p] f32 epilogue, z-batched ----------
__global__ __launch_bounds__(256) void mgemm_proj_kernel(const ushort_t* __restrict__ wp,
                            const ushort_t* __restrict__ at,
                            const float* __restrict__ bias, float* __restrict__ out) {
    __shared__ __align__(16) uint4 smem[2048];   // 32 KB
    uint4* Ah = smem; uint4* Bh = smem + 1024;
    int zb = blockIdx.z;
    const ushort_t* xh = at + (size_t)zb*HW_*256;
    float* outb = out + (size_t)zb*C_*HW_;
    int o0 = blockIdx.x * 128, p0 = blockIdx.y * 128;
    int t = threadIdx.x;
    int lane = t & 63, wid = t >> 6;
    int wm = wid >> 1, wn = wid & 1;
    int q = lane >> 4, rl = lane & 15;

    f32x4 acc[4][4];
    #pragma unroll
    for (int f = 0; f < 4; ++f)
        #pragma unroll
        for (int g = 0; g < 4; ++g)
            acc[f][g] = (f32x4){0.f, 0.f, 0.f, 0.f};

    int srow = t >> 1, shalf = t & 1;
    int sw = srow & 7;

    for (int ks = 0; ks < 4; ++ks) {
        int c0 = ks * 64;
        __syncthreads();
        {
            const uint4* a_h = (const uint4*)(wp + (size_t)(o0+srow)*256 + c0);
            const uint4* b_h = (const uint4*)(xh + (size_t)(p0+srow)*256 + c0);
            #pragma unroll
            for (int jj = 0; jj < 4; ++jj) {
                int u = shalf*4 + jj;
                int d = srow*8 + (u ^ sw);
                Ah[d] = a_h[u]; Bh[d] = b_h[u];
            }
        }
        __syncthreads();
        #pragma unroll
        for (int kk = 0; kk < 2; ++kk) {
            short8 afh[4], bfh[4];
            #pragma unroll
            for (int f = 0; f < 4; ++f) {
                int row = wm*64 + f*16 + rl;
                int u = (kk*4 + q) ^ (row & 7);
                afh[f] = __builtin_bit_cast(short8, Ah[row*8 + u]);
            }
            #pragma unroll
            for (int g = 0; g < 4; ++g) {
                int row = wn*64 + g*16 + rl;
                int u = (kk*4 + q) ^ (row & 7);
                bfh[g] = __builtin_bit_cast(short8, Bh[row*8 + u]);
            }
            #pragma unroll
            for (int f = 0; f < 4; ++f)
                #pragma unroll
                for (int g = 0; g < 4; ++g)
                    acc[f][g] = __builtin_amdgcn_mfma_f32_16x16x32_bf16(afh[f], bfh[g], acc[f][g], 0, 0, 0);
        }
    }
    #pragma unroll
    for (int f = 0; f < 4; ++f) {
        float4 bb = *(const float4*)&bias[o0 + wm*64 + f*16 + q*4];
        float bbv[4] = {bb.x, bb.y, bb.z, bb.w};
        #pragma unroll
        for (int g = 0; g < 4; ++g) {
            int p = p0 + wn*64 + g*16 + rl;
            #pragma unroll
            for (int r = 0; r < 4; ++r) {
                int o = o0 + wm*64 + f*16 + q*4 + r;
                outb[(size_t)o*HW_ + p] = acc[f][g][r] + bbv[r];
            }
        }
    }
}

// ---------- fused bilinear sampling + windowed attention (bf16 qkvt, z-batched) ----------
__global__ __launch_bounds__(256) void attn_kernel(const ushort_t* __restrict__ qkvt,
                            const float* __restrict__ params_,
                            const float* __restrict__ rpb_table,
                            ushort_t* __restrict__ at) {
    __shared__ __align__(16) float q_s[32][68];
    __shared__ __align__(16) float k_s[32][68];
    __shared__ __align__(16) float v_s[32][68];
    __shared__ __align__(16) float S[64][65];
    __shared__ float red[4][64];
    __shared__ float rowm[64], rowinv[64];

    int b = blockIdx.y;
    int blk = blockIdx.x;            // win-major: win*8 + nh
    int win = blk >> 3, nh = blk & 7;
    int wy = win >> 4, wx = win & 15;
    int t = threadIdx.x;

    const float* pp = params_ + ((size_t)((b*8 + nh)*256 + win))*4;
    float ox = pp[0], oy = pp[1], sx = pp[2], sy = pp[3];

    const ushort_t* qkvtb = qkvt + (size_t)b*HW_*768;
    ushort_t* ath = at + (size_t)b*HW_*256;

    {   // load q + bilinear-gather k,v into LDS [d][tok]; channel-last bf16 source
        int tok = t >> 2, dg = (t & 3)*8;
        int i = tok >> 3, j = tok & 7;
        int h = wy*8 + i, w = wx*8 + j;
        size_t p_q = (size_t)h*W_ + w;
        {
            uint4 qu = *(const uint4*)(qkvtb + p_q*768 + nh*32 + dg);
            float qf[8]; bf8_unpack(qu, qf);
            #pragma unroll
            for (int e = 0; e < 8; ++e) q_s[dg+e][tok] = qf[e];
        }
        float gx = (float)w + ((float)j - 3.5f)*sx + ox;
        float gy = (float)h + ((float)i - 3.5f)*sy + oy;
        float x0f = floorf(gx), y0f = floorf(gy);
        int x0 = (int)x0f, y0 = (int)y0f;
        float wx1 = gx - x0f, wy1 = gy - y0f;
        float wxz = 1.f - wx1, wyz = 1.f - wy1;
        int x1 = x0 + 1, y1 = y0 + 1;
        float m00 = wyz*wxz * ((y0>=0 && y0<H_ && x0>=0 && x0<W_) ? 1.f : 0.f);
        float m01 = wyz*wx1 * ((y0>=0 && y0<H_ && x1>=0 && x1<W_) ? 1.f : 0.f);
        float m10 = wy1*wxz * ((y1>=0 && y1<H_ && x0>=0 && x0<W_) ? 1.f : 0.f);
        float m11 = wy1*wx1 * ((y1>=0 && y1<H_ && x1>=0 && x1<W_) ? 1.f : 0.f);
        int x0c = min(max(x0,0),W_-1), x1c = min(max(x1,0),W_-1);
        int y0c = min(max(y0,0),H_-1), y1c = min(max(y1,0),H_-1);
        size_t p00 = (size_t)y0c*W_ + x0c, p01 = (size_t)y0c*W_ + x1c;
        size_t p10 = (size_t)y1c*W_ + x0c, p11 = (size_t)y1c*W_ + x1c;
        float kacc[8], vacc[8];
        #pragma unroll
        for (int e = 0; e < 8; ++e) { kacc[e] = 0.f; vacc[e] = 0.f; }
        int colk = 256 + nh*32 + dg;
        int colv = 512 + nh*32 + dg;
        #define CORNER(PIX, WGT) { \
            const ushort_t* cp = qkvtb + (size_t)(PIX)*768; \
            uint4 ku = *(const uint4*)(cp + colk); \
            uint4 vu = *(const uint4*)(cp + colv); \
            float kf[8], vf[8]; bf8_unpack(ku, kf); bf8_unpack(vu, vf); \
            _Pragma("unroll") \
            for (int e = 0; e < 8; ++e) { kacc[e] += (WGT)*kf[e]; vacc[e] += (WGT)*vf[e]; } }
        CORNER(p00, m00)
        CORNER(p01, m01)
        CORNER(p10, m10)
        CORNER(p11, m11)
        #undef CORNER
        #pragma unroll
        for (int e = 0; e < 8; ++e) {
            k_s[dg+e][tok] = kacc[e];
            v_s[dg+e][tok] = vacc[e];
        }
    }
    __syncthreads();

    const float scale = 0.17677669529663687f;
    {   // S = q.kT * scale + rpb
        int qi0 = (t & 15)*4, ki0 = (t >> 4)*4;
        float acc[4][4];
        #pragma unroll
        for (int a=0;a<4;++a)
            #pragma unroll
            for (int c=0;c<4;++c) acc[a][c]=0.f;
        #pragma unroll
        for (int d = 0; d < 32; ++d) {
            float4 qv = *(const float4*)&q_s[d][qi0];
            float4 kv = *(const float4*)&k_s[d][ki0];
            float qa[4]={qv.x,qv.y,qv.z,qv.w}, ka[4]={kv.x,kv.y,kv.z,kv.w};
            #pragma unroll
            for (int a=0;a<4;++a)
                #pragma unroll
                for (int c=0;c<4;++c) acc[a][c] += qa[a]*ka[c];
        }
        #pragma unroll
        for (int a=0;a<4;++a) {
            int qi = qi0+a; int yq = qi>>3, xq = qi&7;
            #pragma unroll
            for (int c=0;c<4;++c) {
                int ki = ki0+c; int yk = ki>>3, xk = ki&7;
                int idx = (yq-yk+7)*15 + (xq-xk+7);
                S[qi][ki] = acc[a][c]*scale + rpb_table[idx*8 + nh];
            }
        }
    }
    __syncthreads();
    {
        int r = t & 63, part = t >> 6;
        float m = -1e30f;
        #pragma unroll
        for (int c = 0; c < 16; ++c) m = fmaxf(m, S[r][part*16+c]);
        red[part][r] = m;
    }
    __syncthreads();
    if (t < 64) rowm[t] = fmaxf(fmaxf(red[0][t],red[1][t]),fmaxf(red[2][t],red[3][t]));
    __syncthreads();
    {
        int r = t & 63, part = t >> 6;
        float m = rowm[r], s = 0.f;
        #pragma unroll
        for (int c = 0; c < 16; ++c) {
            float e = __expf(S[r][part*16+c] - m);
            S[r][part*16+c] = e;
            s += e;
        }
        red[part][r] = s;
    }
    __syncthreads();
    if (t < 64) rowinv[t] = 1.f / (red[0][t]+red[1][t]+red[2][t]+red[3][t]);
    __syncthreads();
    {   // PV
        int qi0 = (t & 15)*4, d0 = (t >> 4)*2;
        float acc[4][2];
        #pragma unroll
        for (int a=0;a<4;++a) { acc[a][0]=0.f; acc[a][1]=0.f; }
        for (int k = 0; k < 64; ++k) {
            float v0 = v_s[d0][k], v1 = v_s[d0+1][k];
            #pragma unroll
            for (int a=0;a<4;++a) {
                float pv = S[qi0+a][k];
                acc[a][0] += pv*v0; acc[a][1] += pv*v1;
            }
        }
        __syncthreads();  // all P reads done; S reusable
        #pragma unroll
        for (int a=0;a<4;++a) {
            int qi = qi0+a;
            float inv = rowinv[qi];
            S[qi][d0]   = acc[a][0]*inv;
            S[qi][d0+1] = acc[a][1]*inv;
        }
    }
    __syncthreads();
    {   // coalesced bf16 output: [p][256] at col nh*32..+31 (64 pix x 8 ch per thread)
        int pix = t >> 2, cq = (t & 3) * 8;
        int i2 = pix >> 3, j2 = pix & 7;
        size_t prow = (size_t)(wy*8+i2)*W_ + wx*8 + j2;
        uint4 Hv;
        Hv.x = bfpack(S[pix][cq+0], S[pix][cq+1]);
        Hv.y = bfpack(S[pix][cq+2], S[pix][cq+3]);
        Hv.z = bfpack(S[pix][cq+4], S[pix][cq+5]);
        Hv.w = bfpack(S[pix][cq+6], S[pix][cq+7]);
        *(uint4*)(ath + prow*256 + nh*32 + cq) = Hv;
    }
}

extern "C" void kernel_launch(void* const* d_in, const int* in_sizes, int n_in,
                              void* d_out, int out_size, void* d_ws, size_t ws_size,
                              hipStream_t stream) {
    const float* x       = (const float*)d_in[0];
    const float* qkv_w   = (const float*)d_in[1];
    const float* qkv_b   = (const float*)d_in[2];
    const float* bias_w  = (const float*)d_in[3];
    const float* bias_b  = (const float*)d_in[4];
    const float* scale_w = (const float*)d_in[5];
    const float* scale_b = (const float*)d_in[6];
    const float* proj_w  = (const float*)d_in[7];
    const float* proj_b  = (const float*)d_in[8];
    const float* rpb     = (const float*)d_in[9];
    float* out = (float*)d_out;

    // workspace (~180 MB of 512 MiB)
    char* ws = (char*)d_ws;
    float*    xp     = (float*)ws;     ws += (size_t)524288*4;
    float*    params = (float*)ws;     ws += (size_t)65536*4;
    float*    xpart  = (float*)ws;     ws += (size_t)4194304*4;
    ushort_t* wq     = (ushort_t*)ws;  ws += (size_t)768*256*2;
    ushort_t* wp     = (ushort_t*)ws;  ws += (size_t)256*256*2;
    ushort_t* xt     = (ushort_t*)ws;  ws += (size_t)B_*HW_*256*2;
    ushort_t* at     = (ushort_t*)ws;  ws += (size_t)B_*HW_*256*2;
    ushort_t* qkvt   = (ushort_t*)ws;  // B*HW*768*2 = 201 MB

    wconv_kernel<<<dim3(192), 256, 0, stream>>>(qkv_w, wq, 768*256/4);
    wconv_kernel<<<dim3(64),  256, 0, stream>>>(proj_w, wp, 256*256/4);
    transpose_split_kernel<<<dim3(256, 4, B_), 256, 0, stream>>>(x, xt, xpart);
    pool2_kernel <<<dim3(B_*C_), 256, 0, stream>>>(xpart, xp);
    params_kernel<<<dim3(B_*NWIN_), 256, 0, stream>>>(xp, bias_w, bias_b, scale_w, scale_b, params);
    mgemm_qkvt_kernel<<<dim3(6, 128, B_), 256, 0, stream>>>(wq, xt, qkv_b, qkvt);
    attn_kernel<<<dim3(NH_*NWIN_, B_), 256, 0, stream>>>(qkvt, params, rpb, at);
    mgemm_proj_kernel<<<dim3(2, 128, B_), 256, 0, stream>>>(wp, at, proj_b, out);
}

// Round 7
// 435.805 us; speedup vs baseline: 3.1381x; 1.1119x over previous
//
#include <hip/hip_runtime.h>

#define B_ 8
#define C_ 256
#define H_ 128
#define W_ 128
#define NH_ 8
#define WS_ 8
#define HD_ 32
#define WN_ 16
#define NWIN_ 256
#define HW_ 16384

typedef unsigned short ushort_t;
typedef unsigned int uint_t;
typedef __attribute__((ext_vector_type(8))) short short8;
typedef __attribute__((ext_vector_type(4))) float f32x4;

__device__ __forceinline__ ushort_t bf16_rtn(float x) {
    uint_t u = __float_as_uint(x);
    return (ushort_t)((u + 0x7FFFu + ((u >> 16) & 1u)) >> 16);
}
__device__ __forceinline__ uint_t bfpack(float a, float b) {
    return (uint_t)bf16_rtn(a) | ((uint_t)bf16_rtn(b) << 16);
}
__device__ __forceinline__ void bf8_unpack(uint4 u, float* f) {
    f[0]=__uint_as_float((u.x&0xffffu)<<16); f[1]=__uint_as_float(u.x&0xffff0000u);
    f[2]=__uint_as_float((u.y&0xffffu)<<16); f[3]=__uint_as_float(u.y&0xffff0000u);
    f[4]=__uint_as_float((u.z&0xffffu)<<16); f[5]=__uint_as_float(u.z&0xffff0000u);
    f[6]=__uint_as_float((u.w&0xffffu)<<16); f[7]=__uint_as_float(u.w&0xffff0000u);
}

// ---------- weight f32 -> bf16 ----------
__global__ __launch_bounds__(256) void wconv_kernel(const float* __restrict__ w,
                            ushort_t* __restrict__ wh, int n4) {
    int i = blockIdx.x*256 + threadIdx.x;
    if (i >= n4) return;
    float4 v = ((const float4*)w)[i];
    ((uint2*)wh)[i] = make_uint2(bfpack(v.x, v.y), bfpack(v.z, v.w));
}

// ---------- rpb_table -> rpb_full[nh][64][64] ----------
__global__ __launch_bounds__(256) void rpb_expand_kernel(const float* __restrict__ rpb_table,
                            float* __restrict__ rpb_full) {
    int nh = blockIdx.x;
    int t = threadIdx.x;
    #pragma unroll
    for (int rr = 0; rr < 16; ++rr) {
        int e = t*16 + rr;                 // 0..4095
        int qrow = e >> 6, kcol = e & 63;
        int yq = qrow >> 3, xq = qrow & 7, yk = kcol >> 3, xk = kcol & 7;
        int idx = (yq - yk + 7)*15 + (xq - xk + 7);
        rpb_full[((size_t)nh*64 + qrow)*64 + kcol] = rpb_table[idx*8 + nh];
    }
}

// ---------- transpose + bf16 + window-partial-pool, all images ----------
__global__ __launch_bounds__(256) void transpose_split_kernel(const float* __restrict__ x,
                            ushort_t* __restrict__ th, float* __restrict__ xpart) {
    __shared__ float tile[64][65];
    int b = blockIdx.z;
    int p0 = blockIdx.x * 64, c0 = blockIdx.y * 64;
    const float* xsrc = x + (size_t)b*C_*HW_;
    int t = threadIdx.x;
    #pragma unroll
    for (int r = 0; r < 4; ++r) {
        int task = t + r*256;
        int cl = task >> 4, p4 = (task & 15) * 4;
        float4 v = *(const float4*)(xsrc + (size_t)(c0+cl)*HW_ + p0 + p4);
        tile[cl][p4+0] = v.x; tile[cl][p4+1] = v.y; tile[cl][p4+2] = v.z; tile[cl][p4+3] = v.w;
    }
    __syncthreads();
    {
        int h = blockIdx.x >> 1, wbase = (blockIdx.x & 1) * 8;
        #pragma unroll
        for (int r = 0; r < 2; ++r) {
            int task = t + r*256;
            int cl = task >> 3, wx = task & 7;
            float s = 0.f;
            #pragma unroll
            for (int j = 0; j < 8; ++j) s += tile[cl][wx*8+j];
            xpart[(((size_t)b*256 + c0+cl)*128 + h)*16 + wbase + wx] = s;
        }
    }
    ushort_t* thb = th + (size_t)b*HW_*256;
    #pragma unroll
    for (int r = 0; r < 2; ++r) {
        int task = t + r*256;
        int pl = task >> 3, cb = (task & 7) * 8;
        uint4 Hh;
        Hh.x = bfpack(tile[cb+0][pl], tile[cb+1][pl]);
        Hh.y = bfpack(tile[cb+2][pl], tile[cb+3][pl]);
        Hh.z = bfpack(tile[cb+4][pl], tile[cb+5][pl]);
        Hh.w = bfpack(tile[cb+6][pl], tile[cb+7][pl]);
        *(uint4*)(thb + (size_t)(p0+pl)*256 + c0 + cb) = Hh;
    }
}

// ---------- finish pool ----------
__global__ __launch_bounds__(256) void pool2_kernel(const float* __restrict__ xpart, float* __restrict__ xp) {
    int bc = blockIdx.x;
    int t = threadIdx.x;
    int wy = t >> 4, wxg = t & 15;
    const float* src = xpart + (size_t)bc*2048;
    float s = 0.f;
    #pragma unroll
    for (int i = 0; i < 8; ++i) s += src[(wy*8+i)*16 + wxg];
    s *= (1.f/64.f);
    xp[(size_t)bc*256 + t] = s > 0.f ? s : 0.01f*s;
}

// ---------- per-window sampling params ----------
__global__ __launch_bounds__(256) void params_kernel(const float* __restrict__ xp,
                              const float* __restrict__ bias_w, const float* __restrict__ bias_b,
                              const float* __restrict__ scale_w, const float* __restrict__ scale_b,
                              float* __restrict__ params) {
    __shared__ float xs[256];
    int blk = blockIdx.x;
    int b = blk >> 8, win = blk & 255;
    int t = threadIdx.x;
    xs[t] = xp[((size_t)(b*256 + t))*256 + win];
    __syncthreads();
    if (t < 32) {
        int which = t >> 4;
        int o = t & 15;
        const float* Wm = which ? scale_w : bias_w;
        float acc = which ? scale_b[o] : bias_b[o];
        for (int c = 0; c < 256; ++c) acc += Wm[o*256 + c] * xs[c];
        int nh = o >> 1, comp = o & 1;
        int n = b*8 + nh;
        float v = which ? acc : 3.96875f * acc;
        params[((size_t)(n*256 + win))*4 + which*2 + comp] = v;
    }
}

// ---------- single-bf16 MFMA GEMM, channel-last bf16 epilogue, z-batched ----------
__global__ __launch_bounds__(256) void mgemm_qkvt_kernel(const ushort_t* __restrict__ wq,
                            const ushort_t* __restrict__ xt,
                            const float* __restrict__ bias, ushort_t* __restrict__ qkvt) {
    __shared__ __align__(16) uint4 smem[2112];   // 33 KB
    uint4* Ah = smem; uint4* Bh = smem + 1024;
    int zb = blockIdx.z;
    const ushort_t* xh = xt + (size_t)zb*HW_*256;
    ushort_t* outb = qkvt + (size_t)zb*HW_*768;
    int o0 = blockIdx.x * 128, p0 = blockIdx.y * 128;
    int t = threadIdx.x;
    int lane = t & 63, wid = t >> 6;
    int wm = wid >> 1, wn = wid & 1;
    int q = lane >> 4, rl = lane & 15;

    f32x4 acc[4][4];
    #pragma unroll
    for (int f = 0; f < 4; ++f)
        #pragma unroll
        for (int g = 0; g < 4; ++g)
            acc[f][g] = (f32x4){0.f, 0.f, 0.f, 0.f};

    int srow = t >> 1, shalf = t & 1;
    int sw = srow & 7;

    for (int ks = 0; ks < 4; ++ks) {
        int c0 = ks * 64;
        __syncthreads();
        {
            const uint4* a_h = (const uint4*)(wq + (size_t)(o0+srow)*256 + c0);
            const uint4* b_h = (const uint4*)(xh + (size_t)(p0+srow)*256 + c0);
            #pragma unroll
            for (int jj = 0; jj < 4; ++jj) {
                int u = shalf*4 + jj;
                int d = srow*8 + (u ^ sw);
                Ah[d] = a_h[u]; Bh[d] = b_h[u];
            }
        }
        __syncthreads();
        #pragma unroll
        for (int kk = 0; kk < 2; ++kk) {
            short8 afh[4], bfh[4];
            #pragma unroll
            for (int f = 0; f < 4; ++f) {
                int row = wm*64 + f*16 + rl;
                int u = (kk*4 + q) ^ (row & 7);
                afh[f] = __builtin_bit_cast(short8, Ah[row*8 + u]);
            }
            #pragma unroll
            for (int g = 0; g < 4; ++g) {
                int row = wn*64 + g*16 + rl;
                int u = (kk*4 + q) ^ (row & 7);
                bfh[g] = __builtin_bit_cast(short8, Bh[row*8 + u]);
            }
            #pragma unroll
            for (int f = 0; f < 4; ++f)
                #pragma unroll
                for (int g = 0; g < 4; ++g)
                    acc[f][g] = __builtin_amdgcn_mfma_f32_16x16x32_bf16(afh[f], bfh[g], acc[f][g], 0, 0, 0);
        }
    }
    float* tb = (float*)smem;   // [64][129]
    int pl = t >> 1, half = t & 1;
    #pragma unroll
    for (int pass = 0; pass < 2; ++pass) {
        __syncthreads();
        if (wm == pass) {
            #pragma unroll
            for (int f = 0; f < 4; ++f)
                #pragma unroll
                for (int g = 0; g < 4; ++g)
                    #pragma unroll
                    for (int r = 0; r < 4; ++r)
                        tb[(f*16 + q*4 + r)*129 + wn*64 + g*16 + rl] = acc[f][g][r];
        }
        __syncthreads();
        {
            int obase = o0 + pass*64 + half*32;
            ushort_t* dst = outb + (size_t)(p0+pl)*768 + obase;
            #pragma unroll
            for (int u = 0; u < 4; ++u) {
                float v[8];
                #pragma unroll
                for (int e = 0; e < 8; ++e) v[e] = tb[(half*32 + u*8 + e)*129 + pl];
                float4 b0 = *(const float4*)&bias[obase + u*8];
                float4 b1 = *(const float4*)&bias[obase + u*8 + 4];
                uint4 Hv;
                Hv.x = bfpack(v[0]+b0.x, v[1]+b0.y);
                Hv.y = bfpack(v[2]+b0.z, v[3]+b0.w);
                Hv.z = bfpack(v[4]+b1.x, v[5]+b1.y);
                Hv.w = bfpack(v[6]+b1.z, v[7]+b1.w);
                ((uint4*)dst)[u] = Hv;
            }
        }
    }
}

// ---------- single-bf16 MFMA GEMM for proj, z-batched ----------
__global__ __launch_bounds__(256) void mgemm_proj_kernel(const ushort_t* __restrict__ wp,
                            const ushort_t* __restrict__ at,
                            const float* __restrict__ bias, float* __restrict__ out) {
    __shared__ __align__(16) uint4 smem[2048];
    uint4* Ah = smem; uint4* Bh = smem + 1024;
    int zb = blockIdx.z;
    const ushort_t* xh = at + (size_t)zb*HW_*256;
    float* outb = out + (size_t)zb*C_*HW_;
    int o0 = blockIdx.x * 128, p0 = blockIdx.y * 128;
    int t = threadIdx.x;
    int lane = t & 63, wid = t >> 6;
    int wm = wid >> 1, wn = wid & 1;
    int q = lane >> 4, rl = lane & 15;

    f32x4 acc[4][4];
    #pragma unroll
    for (int f = 0; f < 4; ++f)
        #pragma unroll
        for (int g = 0; g < 4; ++g)
            acc[f][g] = (f32x4){0.f, 0.f, 0.f, 0.f};

    int srow = t >> 1, shalf = t & 1;
    int sw = srow & 7;

    for (int ks = 0; ks < 4; ++ks) {
        int c0 = ks * 64;
        __syncthreads();
        {
            const uint4* a_h = (const uint4*)(wp + (size_t)(o0+srow)*256 + c0);
            const uint4* b_h = (const uint4*)(xh + (size_t)(p0+srow)*256 + c0);
            #pragma unroll
            for (int jj = 0; jj < 4; ++jj) {
                int u = shalf*4 + jj;
                int d = srow*8 + (u ^ sw);
                Ah[d] = a_h[u]; Bh[d] = b_h[u];
            }
        }
        __syncthreads();
        #pragma unroll
        for (int kk = 0; kk < 2; ++kk) {
            short8 afh[4], bfh[4];
            #pragma unroll
            for (int f = 0; f < 4; ++f) {
                int row = wm*64 + f*16 + rl;
                int u = (kk*4 + q) ^ (row & 7);
                afh[f] = __builtin_bit_cast(short8, Ah[row*8 + u]);
            }
            #pragma unroll
            for (int g = 0; g < 4; ++g) {
                int row = wn*64 + g*16 + rl;
                int u = (kk*4 + q) ^ (row & 7);
                bfh[g] = __builtin_bit_cast(short8, Bh[row*8 + u]);
            }
            #pragma unroll
            for (int f = 0; f < 4; ++f)
                #pragma unroll
                for (int g = 0; g < 4; ++g)
                    acc[f][g] = __builtin_amdgcn_mfma_f32_16x16x32_bf16(afh[f], bfh[g], acc[f][g], 0, 0, 0);
        }
    }
    #pragma unroll
    for (int f = 0; f < 4; ++f) {
        float4 bb = *(const float4*)&bias[o0 + wm*64 + f*16 + q*4];
        float bbv[4] = {bb.x, bb.y, bb.z, bb.w};
        #pragma unroll
        for (int g = 0; g < 4; ++g) {
            int p = p0 + wn*64 + g*16 + rl;
            #pragma unroll
            for (int r = 0; r < 4; ++r) {
                int o = o0 + wm*64 + f*16 + q*4 + r;
                outb[(size_t)o*HW_ + p] = acc[f][g][r] + bbv[r];
            }
        }
    }
}

// ---------- MFMA fused bilinear sampling + windowed attention ----------
// Q,K LDS [tok][40] bf16 ; V^T [d][72] ; P [qtok][72] ; softmax in-register.
__global__ __launch_bounds__(256) void attn_kernel(const ushort_t* __restrict__ qkvt,
                            const float* __restrict__ params_,
                            const float* __restrict__ rpb_full,
                            ushort_t* __restrict__ at) {
    __shared__ __align__(16) ushort_t Q_lds[64][40];
    __shared__ __align__(16) ushort_t K_lds[64][40];
    __shared__ __align__(16) ushort_t VT_lds[32][72];
    __shared__ __align__(16) ushort_t P_lds[64][72];

    int b = blockIdx.y;
    int blk = blockIdx.x;            // win*8 + nh
    int win = blk >> 3, nh = blk & 7;
    int wy = win >> 4, wx = win & 15;
    int t = threadIdx.x;
    int lane = t & 63, wid = t >> 6;

    const float* pp = params_ + ((size_t)((b*8 + nh)*256 + win))*4;
    float ox = pp[0], oy = pp[1], sx = pp[2], sy = pp[3];

    const ushort_t* qkvtb = qkvt + (size_t)b*HW_*768;
    ushort_t* ath = at + (size_t)b*HW_*256;

    {   // gather: lane = token, wid selects 8-channel group
        int tok = lane, dg = wid*8;
        int i = tok >> 3, j = tok & 7;
        int h = wy*8 + i, w = wx*8 + j;
        size_t p_q = (size_t)h*W_ + w;
        *(uint4*)&Q_lds[tok][dg] = *(const uint4*)(qkvtb + p_q*768 + nh*32 + dg);

        float gx = (float)w + ((float)j - 3.5f)*sx + ox;
        float gy = (float)h + ((float)i - 3.5f)*sy + oy;
        float x0f = floorf(gx), y0f = floorf(gy);
        int x0 = (int)x0f, y0 = (int)y0f;
        float wx1 = gx - x0f, wy1 = gy - y0f;
        float wxz = 1.f - wx1, wyz = 1.f - wy1;
        int x1 = x0 + 1, y1 = y0 + 1;
        float m00 = wyz*wxz * ((y0>=0 && y0<H_ && x0>=0 && x0<W_) ? 1.f : 0.f);
        float m01 = wyz*wx1 * ((y0>=0 && y0<H_ && x1>=0 && x1<W_) ? 1.f : 0.f);
        float m10 = wy1*wxz * ((y1>=0 && y1<H_ && x0>=0 && x0<W_) ? 1.f : 0.f);
        float m11 = wy1*wx1 * ((y1>=0 && y1<H_ && x1>=0 && x1<W_) ? 1.f : 0.f);
        int x0c = min(max(x0,0),W_-1), x1c = min(max(x1,0),W_-1);
        int y0c = min(max(y0,0),H_-1), y1c = min(max(y1,0),H_-1);
        size_t p00 = (size_t)y0c*W_ + x0c, p01 = (size_t)y0c*W_ + x1c;
        size_t p10 = (size_t)y1c*W_ + x0c, p11 = (size_t)y1c*W_ + x1c;
        float kacc[8], vacc[8];
        #pragma unroll
        for (int e = 0; e < 8; ++e) { kacc[e] = 0.f; vacc[e] = 0.f; }
        int colk = 256 + nh*32 + dg;
        int colv = 512 + nh*32 + dg;
        #define CORNER(PIX, WGT) { \
            const ushort_t* cp = qkvtb + (size_t)(PIX)*768; \
            uint4 ku = *(const uint4*)(cp + colk); \
            uint4 vu = *(const uint4*)(cp + colv); \
            float kf[8], vf[8]; bf8_unpack(ku, kf); bf8_unpack(vu, vf); \
            _Pragma("unroll") \
            for (int e = 0; e < 8; ++e) { kacc[e] += (WGT)*kf[e]; vacc[e] += (WGT)*vf[e]; } }
        CORNER(p00, m00)
        CORNER(p01, m01)
        CORNER(p10, m10)
        CORNER(p11, m11)
        #undef CORNER
        uint4 Kv;
        Kv.x = bfpack(kacc[0], kacc[1]); Kv.y = bfpack(kacc[2], kacc[3]);
        Kv.z = bfpack(kacc[4], kacc[5]); Kv.w = bfpack(kacc[6], kacc[7]);
        *(uint4*)&K_lds[tok][dg] = Kv;
        #pragma unroll
        for (int e = 0; e < 8; ++e) VT_lds[dg+e][tok] = bf16_rtn(vacc[e]);
    }
    __syncthreads();

    int q = lane >> 4, rl = lane & 15;
    const float scale = 0.17677669529663687f;

    // QK^T: wave owns m-strip [wid*16, +16)
    short8 a_frag = *(const short8*)&Q_lds[wid*16 + rl][q*8];
    f32x4 accS[4];
    #pragma unroll
    for (int g = 0; g < 4; ++g) {
        short8 b_frag = *(const short8*)&K_lds[g*16 + rl][q*8];
        accS[g] = __builtin_amdgcn_mfma_f32_16x16x32_bf16(a_frag, b_frag, (f32x4){0.f,0.f,0.f,0.f}, 0, 0, 0);
    }
    // S = acc*scale + rpb ; in-register softmax over (rl, g)
    float Sv[4][4];   // [g][r]
    const float* rpbb = rpb_full + (size_t)nh*4096;
    #pragma unroll
    for (int g = 0; g < 4; ++g)
        #pragma unroll
        for (int r = 0; r < 4; ++r) {
            int m = wid*16 + q*4 + r;
            Sv[g][r] = accS[g][r]*scale + rpbb[m*64 + g*16 + rl];
        }
    float inv[4];
    #pragma unroll
    for (int r = 0; r < 4; ++r) {
        float pm = fmaxf(fmaxf(Sv[0][r], Sv[1][r]), fmaxf(Sv[2][r], Sv[3][r]));
        pm = fmaxf(pm, __shfl_xor(pm, 1));
        pm = fmaxf(pm, __shfl_xor(pm, 2));
        pm = fmaxf(pm, __shfl_xor(pm, 4));
        pm = fmaxf(pm, __shfl_xor(pm, 8));
        float s = 0.f;
        #pragma unroll
        for (int g = 0; g < 4; ++g) {
            float e = __expf(Sv[g][r] - pm);
            Sv[g][r] = e;
            s += e;
        }
        s += __shfl_xor(s, 1);
        s += __shfl_xor(s, 2);
        s += __shfl_xor(s, 4);
        s += __shfl_xor(s, 8);
        inv[r] = 1.f / s;
    }
    // normalized P -> LDS bf16
    #pragma unroll
    for (int r = 0; r < 4; ++r) {
        int m = wid*16 + q*4 + r;
        #pragma unroll
        for (int g = 0; g < 4; ++g)
            P_lds[m][g*16 + rl] = bf16_rtn(Sv[g][r]*inv[r]);
    }
    __syncthreads();

    // PV: out[m][d], m-strip wid*16, d = g2*16+rl
    f32x4 accO[2] = {(f32x4){0.f,0.f,0.f,0.f}, (f32x4){0.f,0.f,0.f,0.f}};
    #pragma unroll
    for (int ks = 0; ks < 2; ++ks) {
        short8 p_frag = *(const short8*)&P_lds[wid*16 + rl][ks*32 + q*8];
        #pragma unroll
        for (int g2 = 0; g2 < 2; ++g2) {
            short8 v_frag = *(const short8*)&VT_lds[g2*16 + rl][ks*32 + q*8];
            accO[g2] = __builtin_amdgcn_mfma_f32_16x16x32_bf16(p_frag, v_frag, accO[g2], 0, 0, 0);
        }
    }
    // store: token m = wid*16 + q*4 + r, channel nh*32 + g2*16 + rl
    #pragma unroll
    for (int r = 0; r < 4; ++r) {
        int m = wid*16 + q*4 + r;
        int i2 = m >> 3, j2 = m & 7;
        size_t prow = (size_t)(wy*8 + i2)*W_ + wx*8 + j2;
        #pragma unroll
        for (int g2 = 0; g2 < 2; ++g2)
            ath[prow*256 + nh*32 + g2*16 + rl] = bf16_rtn(accO[g2][r]);
    }
}

extern "C" void kernel_launch(void* const* d_in, const int* in_sizes, int n_in,
                              void* d_out, int out_size, void* d_ws, size_t ws_size,
                              hipStream_t stream) {
    const float* x       = (const float*)d_in[0];
    const float* qkv_w   = (const float*)d_in[1];
    const float* qkv_b   = (const float*)d_in[2];
    const float* bias_w  = (const float*)d_in[3];
    const float* bias_b  = (const float*)d_in[4];
    const float* scale_w = (const float*)d_in[5];
    const float* scale_b = (const float*)d_in[6];
    const float* proj_w  = (const float*)d_in[7];
    const float* proj_b  = (const float*)d_in[8];
    const float* rpb     = (const float*)d_in[9];
    float* out = (float*)d_out;

    // workspace (~180 MB of 512 MiB)
    char* ws = (char*)d_ws;
    float*    xp       = (float*)ws;     ws += (size_t)524288*4;
    float*    params   = (float*)ws;     ws += (size_t)65536*4;
    float*    xpart    = (float*)ws;     ws += (size_t)4194304*4;
    float*    rpb_full = (float*)ws;     ws += (size_t)8*4096*4;
    ushort_t* wq       = (ushort_t*)ws;  ws += (size_t)768*256*2;
    ushort_t* wp       = (ushort_t*)ws;  ws += (size_t)256*256*2;
    ushort_t* xt       = (ushort_t*)ws;  ws += (size_t)B_*HW_*256*2;
    ushort_t* at       = (ushort_t*)ws;  ws += (size_t)B_*HW_*256*2;
    ushort_t* qkvt     = (ushort_t*)ws;  // B*HW*768*2 = 201 MB

    wconv_kernel<<<dim3(192), 256, 0, stream>>>(qkv_w, wq, 768*256/4);
    wconv_kernel<<<dim3(64),  256, 0, stream>>>(proj_w, wp, 256*256/4);
    rpb_expand_kernel<<<dim3(NH_), 256, 0, stream>>>(rpb, rpb_full);
    transpose_split_kernel<<<dim3(256, 4, B_), 256, 0, stream>>>(x, xt, xpart);
    pool2_kernel <<<dim3(B_*C_), 256, 0, stream>>>(xpart, xp);
    params_kernel<<<dim3(B_*NWIN_), 256, 0, stream>>>(xp, bias_w, bias_b, scale_w, scale_b, params);
    mgemm_qkvt_kernel<<<dim3(6, 128, B_), 256, 0, stream>>>(wq, xt, qkv_b, qkvt);
    attn_kernel<<<dim3(NH_*NWIN_, B_), 256, 0, stream>>>(qkvt, params, rpb_full, at);
    mgemm_proj_kernel<<<dim3(2, 128, B_), 256, 0, stream>>>(wp, at, proj_b, out);
}